// Round 11
// baseline (1113.016 us; speedup 1.0000x reference)
//
#include <hip/hip_runtime.h>

#define N_AUTHOR 100000
#define N_FOS    30000
#define N_INST   8000
#define N_PAPER  200000
#define NCNT     838000
#define ETOT     3300000

#define NBA 1563   // (N_AUTHOR+63)/64
#define NBF 469
#define NBI 125
#define NBP 3125
#define NB_TOTAL (NBP + NBA + NBF + NBI)

#define B_AFF    0
#define B_ITA    8000
#define B_WRITES 108000
#define B_PTA    308000
#define B_CITES  408000
#define B_TOPIC  608000
#define B_FTP    638000

typedef __attribute__((ext_vector_type(8))) short short8v;
typedef __attribute__((ext_vector_type(4))) float float4v;
typedef unsigned short us;

__device__ __forceinline__ us f2bf(float f) {
  unsigned u = __float_as_uint(f);
  u = u + 0x7fffu + ((u >> 16) & 1u);
  return (us)(u >> 16);
}
#define BF2F(s) __uint_as_float(((unsigned)(us)(s)) << 16)

__device__ __forceinline__ void acc8(float4v& x, float4v& y, short8v h) {
  x[0] += BF2F(h[0]); x[1] += BF2F(h[1]); x[2] += BF2F(h[2]); x[3] += BF2F(h[3]);
  y[0] += BF2F(h[4]); y[1] += BF2F(h[5]); y[2] += BF2F(h[6]); y[3] += BF2F(h[7]);
}

__device__ __forceinline__ short8v pack8(float4v a, float4v b) {
  short8v h;
  h[0] = (short)f2bf(a[0]); h[1] = (short)f2bf(a[1]);
  h[2] = (short)f2bf(a[2]); h[3] = (short)f2bf(a[3]);
  h[4] = (short)f2bf(b[0]); h[5] = (short)f2bf(b[1]);
  h[6] = (short)f2bf(b[2]); h[7] = (short)f2bf(b[3]);
  return h;
}

// ---------------- workspace layout (bytes) ----------------
#define O_CNT    0
#define O_OFFS   3352000
#define O_CURSOR 6704000
#define O_BTOT   10056000
#define O_CSR    10060096
#define O_WT     23260096
#define XB_AUTHOR 23620544
#define XB_FOS    49220544
#define XB_INST   56900544
#define XB_PAPER  58948544
#define WS_NEED_BF 110148544ULL

struct RelTab { const int* src; const int* dst; int E; int base; };
struct Rels { RelTab r[7]; };
struct WPtrs { const float* w[11]; };
struct XCvt { const float* x; us* xb; int n8; };

__global__ void prep(WPtrs P, us* __restrict__ wt,
                     int* __restrict__ cnt, XCvt x0, XCvt x1, XCvt x2, XCvt x3,
                     Rels R, int doX) {
  int gsz = gridDim.x * blockDim.x;
  int gtid = blockIdx.x * blockDim.x + threadIdx.x;
  for (int i = gtid; i < 11 * 16384; i += gsz) {
    int mat = i >> 14, rem = i & 16383;
    int k = rem >> 7, n = rem & 127;
    wt[mat * 16384 + n * 128 + k] = f2bf(P.w[mat][rem]);
  }
  if (doX) {
    XCvt xc[4] = {x0, x1, x2, x3};
    #pragma unroll
    for (int a = 0; a < 4; ++a) {
      const float* xp = xc[a].x;
      short8v* xbp = (short8v*)xc[a].xb;
      int n8 = xc[a].n8;
      for (int i = gtid; i < n8; i += gsz) {
        float4v v0 = *(const float4v*)(xp + (size_t)i * 8);
        float4v v1 = *(const float4v*)(xp + (size_t)i * 8 + 4);
        xbp[i] = pack8(v0, v1);
      }
    }
  }
  #pragma unroll
  for (int rr = 0; rr < 7; ++rr) {
    const int* dst = R.r[rr].dst;
    int E = R.r[rr].E, base = R.r[rr].base;
    for (int e = gtid; e < E; e += gsz) atomicAdd(&cnt[base + dst[e]], 1);
  }
}

__global__ void scan1(const int* __restrict__ cnt, int* __restrict__ offs,
                      int* __restrict__ btot, int n) {
  __shared__ int sh[256];
  int tid = threadIdx.x;
  int base = blockIdx.x * 2048 + tid * 8;
  int v[8]; int s = 0;
  #pragma unroll
  for (int i = 0; i < 8; ++i) { v[i] = (base + i < n) ? cnt[base + i] : 0; s += v[i]; }
  sh[tid] = s; __syncthreads();
  for (int off = 1; off < 256; off <<= 1) {
    int t = (tid >= off) ? sh[tid - off] : 0;
    __syncthreads();
    sh[tid] += t;
    __syncthreads();
  }
  int excl = sh[tid] - s;
  if (tid == 255) btot[blockIdx.x] = sh[255];
  int run = excl;
  #pragma unroll
  for (int i = 0; i < 8; ++i) { if (base + i < n) offs[base + i] = run; run += v[i]; }
}

__global__ void scan23(int* __restrict__ offs, int* __restrict__ cursor,
                       const int* __restrict__ btot, int nb, int n) {
  __shared__ int sh[512];
  int tid = threadIdx.x;
  int v = (tid < nb) ? btot[tid] : 0;
  sh[tid] = v; __syncthreads();
  for (int off = 1; off < 512; off <<= 1) {
    int t = (tid >= off) ? sh[tid - off] : 0;
    __syncthreads();
    sh[tid] += t;
    __syncthreads();
  }
  int excl = sh[tid] - v;
  __syncthreads();
  sh[tid] = excl;
  __syncthreads();
  int gsz = gridDim.x * 512;
  for (int idx = blockIdx.x * 512 + tid; idx < n; idx += gsz) {
    int val = offs[idx] + sh[idx >> 11];
    offs[idx] = val;
    cursor[idx] = val;
  }
}

__global__ void fill_k(Rels R, int* __restrict__ cursor, int* __restrict__ csr) {
  int gsz = gridDim.x * blockDim.x;
  int gtid = blockIdx.x * blockDim.x + threadIdx.x;
  #pragma unroll
  for (int rr = 0; rr < 7; ++rr) {
    const int* src = R.r[rr].src;
    const int* dst = R.r[rr].dst;
    int E = R.r[rr].E, base = R.r[rr].base;
    for (int e = gtid; e < E; e += gsz) {
      int p = atomicAdd(&cursor[base + dst[e]], 1);
      csr[p] = src[e];
    }
  }
}

// ---------------- fused gather-GEMM body (compile-time args) ----------------
template <int NSRC>
__device__ __forceinline__ void fused_body(
    const us* __restrict__ x0, const us* __restrict__ x1,
    const us* __restrict__ x2, const us* __restrict__ x3,
    const us* __restrict__ w0, const us* __restrict__ w1,
    const us* __restrict__ w2, const us* __restrict__ w3,
    int b1, int b2, int b3,
    const int* __restrict__ offs, const int* __restrict__ cnt,
    const int* __restrict__ csr,
    const float* __restrict__ bias, float* __restrict__ out, int n, int rb0) {
  const int lane = threadIdx.x & 63;
  const int wv = threadIdx.x >> 6;
  const int rb = rb0 + wv * 16;
  int ar = rb + (lane & 15); if (ar >= n) ar = n - 1;
  const int cw = (lane >> 4) * 8;

  const us* xs[4] = {x0, x1, x2, x3};
  const us* wsp[4] = {w0, w1, w2, w3};
  const int bases[4] = {0, b1, b2, b3};

  float4v acc[8];
  #pragma unroll
  for (int i = 0; i < 8; ++i) acc[i] = (float4v)0.0f;

  #pragma unroll
  for (int kb = 0; kb < NSRC; ++kb) {
    short8v af[4];
    if (kb == 0) {
      const us* rp = xs[0] + (size_t)ar * 128 + cw;
      #pragma unroll
      for (int ks = 0; ks < 4; ++ks)
        af[ks] = *(const short8v*)(rp + ks * 32);
    } else {
      int gd = bases[kb] + ar;
      int st = offs[gd];
      int deg = cnt[gd];
      const us* xb = xs[kb];
      float4v a0[4], a1[4];
      #pragma unroll
      for (int ks = 0; ks < 4; ++ks) { a0[ks] = (float4v)0.f; a1[ks] = (float4v)0.f; }
      int j = 0;
      for (; j + 4 <= deg; j += 4) {
        int s0 = csr[st + j],     s1 = csr[st + j + 1];
        int s2 = csr[st + j + 2], s3 = csr[st + j + 3];
        const us* p0 = xb + (size_t)s0 * 128 + cw;
        const us* p1 = xb + (size_t)s1 * 128 + cw;
        const us* p2 = xb + (size_t)s2 * 128 + cw;
        const us* p3 = xb + (size_t)s3 * 128 + cw;
        #pragma unroll
        for (int ks = 0; ks < 4; ++ks) {
          short8v h0 = *(const short8v*)(p0 + ks * 32);
          short8v h1 = *(const short8v*)(p1 + ks * 32);
          short8v h2 = *(const short8v*)(p2 + ks * 32);
          short8v h3 = *(const short8v*)(p3 + ks * 32);
          acc8(a0[ks], a1[ks], h0);
          acc8(a0[ks], a1[ks], h1);
          acc8(a0[ks], a1[ks], h2);
          acc8(a0[ks], a1[ks], h3);
        }
      }
      for (; j < deg; ++j) {
        int s0 = csr[st + j];
        const us* p0 = xb + (size_t)s0 * 128 + cw;
        #pragma unroll
        for (int ks = 0; ks < 4; ++ks) {
          short8v h0 = *(const short8v*)(p0 + ks * 32);
          acc8(a0[ks], a1[ks], h0);
        }
      }
      float sc = 1.0f / (float)((deg > 0) ? deg : 1);
      #pragma unroll
      for (int ks = 0; ks < 4; ++ks)
        af[ks] = pack8(a0[ks] * sc, a1[ks] * sc);
    }
    const us* wb = wsp[kb] + (size_t)(lane & 15) * 128 + cw;
    #pragma unroll
    for (int ct = 0; ct < 8; ++ct) {
      short8v bfr[4];
      #pragma unroll
      for (int ks = 0; ks < 4; ++ks)
        bfr[ks] = *(const short8v*)(wb + ct * 2048 + ks * 32);
      #pragma unroll
      for (int ks = 0; ks < 4; ++ks)
        acc[ct] = __builtin_amdgcn_mfma_f32_16x16x32_bf16(af[ks], bfr[ks], acc[ct], 0, 0, 0);
    }
  }
  #pragma unroll
  for (int ct = 0; ct < 8; ++ct) {
    #pragma unroll
    for (int i = 0; i < 4; ++i) {
      int g = rb + (lane >> 4) * 4 + i;
      if (g < n) {
        int col = ct * 16 + (lane & 15);
        out[(size_t)g * 128 + col] = acc[ct][i] + bias[col];
      }
    }
  }
}

// single merged launch; block ranges are compile-time; paper first (biggest)
__global__ __launch_bounds__(256, 8) void fused_all(
    const us* __restrict__ xbA, const us* __restrict__ xbF,
    const us* __restrict__ xbI, const us* __restrict__ xbP,
    const us* __restrict__ wt,
    const int* __restrict__ offs, const int* __restrict__ cnt,
    const int* __restrict__ csr,
    const float* __restrict__ bA, const float* __restrict__ bF,
    const float* __restrict__ bI, const float* __restrict__ bP,
    float* __restrict__ out) {
  const int bid = blockIdx.x;
  if (bid < NBP) {
    fused_body<4>(xbP, xbA, xbP, xbF,
                  wt + 3 * 16384, wt + 6 * 16384, wt + 8 * 16384, wt + 10 * 16384,
                  B_WRITES, B_CITES, B_FTP, offs, cnt, csr,
                  bP, out + (size_t)138000 * 128, N_PAPER, bid * 64);
  } else if (bid < NBP + NBA) {
    fused_body<3>(xbA, xbI, xbP, nullptr,
                  wt + 0 * 16384, wt + 5 * 16384, wt + 7 * 16384, nullptr,
                  B_ITA, B_PTA, 0, offs, cnt, csr,
                  bA, out, N_AUTHOR, (bid - NBP) * 64);
  } else if (bid < NBP + NBA + NBF) {
    fused_body<2>(xbF, xbP, nullptr, nullptr,
                  wt + 1 * 16384, wt + 9 * 16384, nullptr, nullptr,
                  B_TOPIC, 0, 0, offs, cnt, csr,
                  bF, out + (size_t)100000 * 128, N_FOS, (bid - NBP - NBA) * 64);
  } else {
    fused_body<2>(xbI, xbA, nullptr, nullptr,
                  wt + 2 * 16384, wt + 4 * 16384, nullptr, nullptr,
                  B_AFF, 0, 0, offs, cnt, csr,
                  bI, out + (size_t)130000 * 128, N_INST, (bid - NBP - NBA - NBF) * 64);
  }
}

// ---------------- fp32 fallback (small ws) ----------------------------------
typedef float4v f4;
__global__ __launch_bounds__(256, 4) void fb_gemm(
    const float* __restrict__ x0, const float* __restrict__ x1,
    const float* __restrict__ x2, const float* __restrict__ x3,
    const us* __restrict__ w0, const us* __restrict__ w1,
    const us* __restrict__ w2, const us* __restrict__ w3,
    int nsrc, int b1, int b2, int b3,
    const int* __restrict__ offs, const int* __restrict__ cnt,
    const int* __restrict__ csr,
    const float* __restrict__ bias, float* __restrict__ out, int n) {
  const int lane = threadIdx.x & 63;
  const int wv = threadIdx.x >> 6;
  const int rb = blockIdx.x * 64 + wv * 16;
  int ar = rb + (lane & 15); if (ar >= n) ar = n - 1;
  const int cw = (lane >> 4) * 8;
  const float* xs[4] = {x0, x1, x2, x3};
  const us* wsp[4] = {w0, w1, w2, w3};
  const int bases[4] = {0, b1, b2, b3};
  float4v acc[8];
  #pragma unroll
  for (int i = 0; i < 8; ++i) acc[i] = (float4v)0.0f;
  for (int kb = 0; kb < nsrc; ++kb) {
    short8v af[4];
    const float* xb = xs[kb];
    if (kb == 0) {
      const float* rp = xb + (size_t)ar * 128 + cw;
      #pragma unroll
      for (int ks = 0; ks < 4; ++ks) {
        f4 u = *(const f4*)(rp + ks * 32);
        f4 v = *(const f4*)(rp + ks * 32 + 4);
        af[ks] = pack8(u, v);
      }
    } else {
      int gd = bases[kb] + ar;
      int st = offs[gd];
      int deg = cnt[gd];
      f4 a0[4], a1[4];
      #pragma unroll
      for (int ks = 0; ks < 4; ++ks) { a0[ks] = (f4)0.f; a1[ks] = (f4)0.f; }
      for (int j = 0; j < deg; ++j) {
        int s0 = csr[st + j];
        const float* p0 = xb + (size_t)s0 * 128 + cw;
        #pragma unroll
        for (int ks = 0; ks < 4; ++ks) {
          a0[ks] += *(const f4*)(p0 + ks * 32);
          a1[ks] += *(const f4*)(p0 + ks * 32 + 4);
        }
      }
      float sc = 1.0f / (float)((deg > 0) ? deg : 1);
      #pragma unroll
      for (int ks = 0; ks < 4; ++ks)
        af[ks] = pack8(a0[ks] * sc, a1[ks] * sc);
    }
    const us* wb = wsp[kb] + (size_t)(lane & 15) * 128 + cw;
    #pragma unroll
    for (int ct = 0; ct < 8; ++ct) {
      short8v bfr[4];
      #pragma unroll
      for (int ks = 0; ks < 4; ++ks)
        bfr[ks] = *(const short8v*)(wb + ct * 2048 + ks * 32);
      #pragma unroll
      for (int ks = 0; ks < 4; ++ks)
        acc[ct] = __builtin_amdgcn_mfma_f32_16x16x32_bf16(af[ks], bfr[ks], acc[ct], 0, 0, 0);
    }
  }
  #pragma unroll
  for (int ct = 0; ct < 8; ++ct) {
    #pragma unroll
    for (int i = 0; i < 4; ++i) {
      int g = rb + (lane >> 4) * 4 + i;
      if (g < n) {
        int col = ct * 16 + (lane & 15);
        out[(size_t)g * 128 + col] = acc[ct][i] + bias[col];
      }
    }
  }
}

extern "C" void kernel_launch(void* const* d_in, const int* in_sizes, int n_in,
                              void* d_out, int out_size, void* d_ws, size_t ws_size,
                              hipStream_t stream) {
  const float* x_author = (const float*)d_in[0];
  const float* x_fos    = (const float*)d_in[1];
  const float* x_inst   = (const float*)d_in[2];
  const float* x_paper  = (const float*)d_in[3];

  Rels R;
  const int E[7]  = {150000, 150000, 500000, 500000, 1000000, 500000, 500000};
  const int ND[7] = {N_INST, N_AUTHOR, N_PAPER, N_AUTHOR, N_PAPER, N_FOS, N_PAPER};
  int base = 0;
  for (int r = 0; r < 7; ++r) {
    R.r[r].src = (const int*)d_in[4 + 2 * r];
    R.r[r].dst = (const int*)d_in[5 + 2 * r];
    R.r[r].E = E[r];
    R.r[r].base = base;
    base += ND[r];
  }

  char* ws = (char*)d_ws;
  int* cnt    = (int*)(ws + O_CNT);
  int* offs   = (int*)(ws + O_OFFS);
  int* cursor = (int*)(ws + O_CURSOR);
  int* btot   = (int*)(ws + O_BTOT);
  int* csr    = (int*)(ws + O_CSR);
  us* wt  = (us*)(ws + O_WT);
  us* xbA = (us*)(ws + XB_AUTHOR);
  us* xbF = (us*)(ws + XB_FOS);
  us* xbI = (us*)(ws + XB_INST);
  us* xbP = (us*)(ws + XB_PAPER);

  const int useBF = (ws_size >= WS_NEED_BF) ? 1 : 0;

  WPtrs WP;
  WP.w[0] = (const float*)d_in[18];
  WP.w[1] = (const float*)d_in[20];
  WP.w[2] = (const float*)d_in[22];
  WP.w[3] = (const float*)d_in[24];
  for (int r = 0; r < 7; ++r) WP.w[4 + r] = (const float*)d_in[26 + r];

  XCvt xcA = {x_author, xbA, N_AUTHOR * 16};
  XCvt xcF = {x_fos,    xbF, N_FOS * 16};
  XCvt xcI = {x_inst,   xbI, N_INST * 16};
  XCvt xcP = {x_paper,  xbP, N_PAPER * 16};

  hipMemsetAsync(cnt, 0, (size_t)NCNT * 4, stream);
  prep<<<2048, 256, 0, stream>>>(WP, wt, cnt, xcA, xcF, xcI, xcP, R, useBF);
  scan1<<<410, 256, 0, stream>>>(cnt, offs, btot, NCNT);
  scan23<<<1024, 512, 0, stream>>>(offs, cursor, btot, 410, NCNT);
  fill_k<<<2048, 256, 0, stream>>>(R, cursor, csr);

  float* out = (float*)d_out;
  const float* bA = (const float*)d_in[19];
  const float* bF = (const float*)d_in[21];
  const float* bI = (const float*)d_in[23];
  const float* bP = (const float*)d_in[25];

  if (useBF) {
    fused_all<<<NB_TOTAL, 256, 0, stream>>>(xbA, xbF, xbI, xbP, wt,
                                            offs, cnt, csr,
                                            bA, bF, bI, bP, out);
  } else {
    fb_gemm<<<NBA, 256, 0, stream>>>(
        x_author, x_inst, x_paper, nullptr,
        wt + 0 * 16384, wt + 5 * 16384, wt + 7 * 16384, nullptr,
        3, B_ITA, B_PTA, 0, offs, cnt, csr, bA, out, N_AUTHOR);
    fb_gemm<<<NBF, 256, 0, stream>>>(
        x_fos, x_paper, nullptr, nullptr,
        wt + 1 * 16384, wt + 9 * 16384, nullptr, nullptr,
        2, B_TOPIC, 0, 0, offs, cnt, csr, bF, out + (size_t)100000 * 128, N_FOS);
    fb_gemm<<<NBI, 256, 0, stream>>>(
        x_inst, x_author, nullptr, nullptr,
        wt + 2 * 16384, wt + 4 * 16384, nullptr, nullptr,
        2, B_AFF, 0, 0, offs, cnt, csr, bI, out + (size_t)130000 * 128, N_INST);
    fb_gemm<<<NBP, 256, 0, stream>>>(
        x_paper, x_author, x_paper, x_fos,
        wt + 3 * 16384, wt + 6 * 16384, wt + 8 * 16384, wt + 10 * 16384,
        4, B_WRITES, B_CITES, B_FTP, offs, cnt, csr, bP,
        out + (size_t)138000 * 128, N_PAPER);
  }
}

// Round 12
// 895.065 us; speedup vs baseline: 1.2435x; 1.2435x over previous
//
#include <hip/hip_runtime.h>

#define N_AUTHOR 100000
#define N_FOS    30000
#define N_INST   8000
#define N_PAPER  200000
#define NCNT     838000
#define ETOT     3300000

#define NBA 1563   // (N_AUTHOR+63)/64
#define NBF 469
#define NBI 125
#define NBP 3125
#define NB_TOTAL (NBP + NBA + NBF + NBI)

#define B_AFF    0
#define B_ITA    8000
#define B_WRITES 108000
#define B_PTA    308000
#define B_CITES  408000
#define B_TOPIC  608000
#define B_FTP    638000

typedef __attribute__((ext_vector_type(8))) short short8v;
typedef __attribute__((ext_vector_type(4))) float float4v;
typedef unsigned short us;

__device__ __forceinline__ us f2bf(float f) {
  unsigned u = __float_as_uint(f);
  u = u + 0x7fffu + ((u >> 16) & 1u);
  return (us)(u >> 16);
}
#define BF2F(s) __uint_as_float(((unsigned)(us)(s)) << 16)

__device__ __forceinline__ void acc8(float4v& x, float4v& y, short8v h) {
  x[0] += BF2F(h[0]); x[1] += BF2F(h[1]); x[2] += BF2F(h[2]); x[3] += BF2F(h[3]);
  y[0] += BF2F(h[4]); y[1] += BF2F(h[5]); y[2] += BF2F(h[6]); y[3] += BF2F(h[7]);
}

__device__ __forceinline__ short8v pack8(float4v a, float4v b) {
  short8v h;
  h[0] = (short)f2bf(a[0]); h[1] = (short)f2bf(a[1]);
  h[2] = (short)f2bf(a[2]); h[3] = (short)f2bf(a[3]);
  h[4] = (short)f2bf(b[0]); h[5] = (short)f2bf(b[1]);
  h[6] = (short)f2bf(b[2]); h[7] = (short)f2bf(b[3]);
  return h;
}

// ---------------- workspace layout (bytes) ----------------
#define O_CNT    0
#define O_OFFS   3352000
#define O_CURSOR 6704000
#define O_BTOT   10056000
#define O_CSR    10060096
#define O_WT     23260096
#define XB_AUTHOR 23620544
#define XB_FOS    49220544
#define XB_INST   56900544
#define XB_PAPER  58948544
#define WS_NEED_BF 110148544ULL

struct RelTab { const int* src; const int* dst; int E; int base; };
struct Rels { RelTab r[7]; };
struct WPtrs { const float* w[11]; };
struct XCvt { const float* x; us* xb; int n8; };

__global__ void prep(WPtrs P, us* __restrict__ wt,
                     int* __restrict__ cnt, XCvt x0, XCvt x1, XCvt x2, XCvt x3,
                     Rels R, int doX) {
  int gsz = gridDim.x * blockDim.x;
  int gtid = blockIdx.x * blockDim.x + threadIdx.x;
  for (int i = gtid; i < 11 * 16384; i += gsz) {
    int mat = i >> 14, rem = i & 16383;
    int k = rem >> 7, n = rem & 127;
    wt[mat * 16384 + n * 128 + k] = f2bf(P.w[mat][rem]);
  }
  if (doX) {
    XCvt xc[4] = {x0, x1, x2, x3};
    #pragma unroll
    for (int a = 0; a < 4; ++a) {
      const float* xp = xc[a].x;
      short8v* xbp = (short8v*)xc[a].xb;
      int n8 = xc[a].n8;
      for (int i = gtid; i < n8; i += gsz) {
        float4v v0 = *(const float4v*)(xp + (size_t)i * 8);
        float4v v1 = *(const float4v*)(xp + (size_t)i * 8 + 4);
        xbp[i] = pack8(v0, v1);
      }
    }
  }
  #pragma unroll
  for (int rr = 0; rr < 7; ++rr) {
    const int* dst = R.r[rr].dst;
    int E = R.r[rr].E, base = R.r[rr].base;
    for (int e = gtid; e < E; e += gsz) atomicAdd(&cnt[base + dst[e]], 1);
  }
}

__global__ void scan1(const int* __restrict__ cnt, int* __restrict__ offs,
                      int* __restrict__ btot, int n) {
  __shared__ int sh[256];
  int tid = threadIdx.x;
  int base = blockIdx.x * 2048 + tid * 8;
  int v[8]; int s = 0;
  #pragma unroll
  for (int i = 0; i < 8; ++i) { v[i] = (base + i < n) ? cnt[base + i] : 0; s += v[i]; }
  sh[tid] = s; __syncthreads();
  for (int off = 1; off < 256; off <<= 1) {
    int t = (tid >= off) ? sh[tid - off] : 0;
    __syncthreads();
    sh[tid] += t;
    __syncthreads();
  }
  int excl = sh[tid] - s;
  if (tid == 255) btot[blockIdx.x] = sh[255];
  int run = excl;
  #pragma unroll
  for (int i = 0; i < 8; ++i) { if (base + i < n) offs[base + i] = run; run += v[i]; }
}

__global__ void scan23(int* __restrict__ offs, int* __restrict__ cursor,
                       const int* __restrict__ btot, int nb, int n) {
  __shared__ int sh[512];
  int tid = threadIdx.x;
  int v = (tid < nb) ? btot[tid] : 0;
  sh[tid] = v; __syncthreads();
  for (int off = 1; off < 512; off <<= 1) {
    int t = (tid >= off) ? sh[tid - off] : 0;
    __syncthreads();
    sh[tid] += t;
    __syncthreads();
  }
  int excl = sh[tid] - v;
  __syncthreads();
  sh[tid] = excl;
  __syncthreads();
  int gsz = gridDim.x * 512;
  for (int idx = blockIdx.x * 512 + tid; idx < n; idx += gsz) {
    int val = offs[idx] + sh[idx >> 11];
    offs[idx] = val;
    cursor[idx] = val;
  }
}

__global__ void fill_k(Rels R, int* __restrict__ cursor, int* __restrict__ csr) {
  int gsz = gridDim.x * blockDim.x;
  int gtid = blockIdx.x * blockDim.x + threadIdx.x;
  #pragma unroll
  for (int rr = 0; rr < 7; ++rr) {
    const int* src = R.r[rr].src;
    const int* dst = R.r[rr].dst;
    int E = R.r[rr].E, base = R.r[rr].base;
    for (int e = gtid; e < E; e += gsz) {
      int p = atomicAdd(&cursor[base + dst[e]], 1);
      csr[p] = src[e];
    }
  }
}

// ---------------- fused gather-GEMM body (2-edge batching, low pressure) ----
template <int NSRC>
__device__ __forceinline__ void fused_body(
    const us* __restrict__ x0, const us* __restrict__ x1,
    const us* __restrict__ x2, const us* __restrict__ x3,
    const us* __restrict__ w0, const us* __restrict__ w1,
    const us* __restrict__ w2, const us* __restrict__ w3,
    int b1, int b2, int b3,
    const int* __restrict__ offs, const int* __restrict__ cnt,
    const int* __restrict__ csr,
    const float* __restrict__ bias, float* __restrict__ out, int n, int rb0) {
  const int lane = threadIdx.x & 63;
  const int wv = threadIdx.x >> 6;
  const int rb = rb0 + wv * 16;
  int ar = rb + (lane & 15); if (ar >= n) ar = n - 1;
  const int cw = (lane >> 4) * 8;

  const us* xs[4] = {x0, x1, x2, x3};
  const us* wsp[4] = {w0, w1, w2, w3};
  const int bases[4] = {0, b1, b2, b3};

  float4v acc[8];
  #pragma unroll
  for (int i = 0; i < 8; ++i) acc[i] = (float4v)0.0f;

  #pragma unroll
  for (int kb = 0; kb < NSRC; ++kb) {
    short8v af[4];
    if (kb == 0) {
      const us* rp = xs[0] + (size_t)ar * 128 + cw;
      #pragma unroll
      for (int ks = 0; ks < 4; ++ks)
        af[ks] = *(const short8v*)(rp + ks * 32);
    } else {
      int gd = bases[kb] + ar;
      int st = offs[gd];
      int deg = cnt[gd];
      const us* xb = xs[kb];
      float4v a0[4], a1[4];
      #pragma unroll
      for (int ks = 0; ks < 4; ++ks) { a0[ks] = (float4v)0.f; a1[ks] = (float4v)0.f; }
      int j = 0;
      for (; j + 2 <= deg; j += 2) {
        int s0 = csr[st + j], s1 = csr[st + j + 1];
        const us* p0 = xb + (size_t)s0 * 128 + cw;
        const us* p1 = xb + (size_t)s1 * 128 + cw;
        #pragma unroll
        for (int ks = 0; ks < 4; ++ks) {
          short8v h0 = *(const short8v*)(p0 + ks * 32);
          short8v h1 = *(const short8v*)(p1 + ks * 32);
          acc8(a0[ks], a1[ks], h0);
          acc8(a0[ks], a1[ks], h1);
        }
      }
      if (j < deg) {
        int s0 = csr[st + j];
        const us* p0 = xb + (size_t)s0 * 128 + cw;
        #pragma unroll
        for (int ks = 0; ks < 4; ++ks) {
          short8v h0 = *(const short8v*)(p0 + ks * 32);
          acc8(a0[ks], a1[ks], h0);
        }
      }
      float sc = 1.0f / (float)((deg > 0) ? deg : 1);
      #pragma unroll
      for (int ks = 0; ks < 4; ++ks)
        af[ks] = pack8(a0[ks] * sc, a1[ks] * sc);
    }
    const us* wb = wsp[kb] + (size_t)(lane & 15) * 128 + cw;
    #pragma unroll
    for (int ct = 0; ct < 8; ++ct) {
      short8v bfr[4];
      #pragma unroll
      for (int ks = 0; ks < 4; ++ks)
        bfr[ks] = *(const short8v*)(wb + ct * 2048 + ks * 32);
      #pragma unroll
      for (int ks = 0; ks < 4; ++ks)
        acc[ct] = __builtin_amdgcn_mfma_f32_16x16x32_bf16(af[ks], bfr[ks], acc[ct], 0, 0, 0);
    }
  }
  #pragma unroll
  for (int ct = 0; ct < 8; ++ct) {
    #pragma unroll
    for (int i = 0; i < 4; ++i) {
      int g = rb + (lane >> 4) * 4 + i;
      if (g < n) {
        int col = ct * 16 + (lane & 15);
        out[(size_t)g * 128 + col] = acc[ct][i] + bias[col];
      }
    }
  }
}

// single merged launch; compile-time block ranges; paper first (biggest)
__global__ __launch_bounds__(256, 6) void fused_all(
    const us* __restrict__ xbA, const us* __restrict__ xbF,
    const us* __restrict__ xbI, const us* __restrict__ xbP,
    const us* __restrict__ wt,
    const int* __restrict__ offs, const int* __restrict__ cnt,
    const int* __restrict__ csr,
    const float* __restrict__ bA, const float* __restrict__ bF,
    const float* __restrict__ bI, const float* __restrict__ bP,
    float* __restrict__ out) {
  const int bid = blockIdx.x;
  if (bid < NBP) {
    fused_body<4>(xbP, xbA, xbP, xbF,
                  wt + 3 * 16384, wt + 6 * 16384, wt + 8 * 16384, wt + 10 * 16384,
                  B_WRITES, B_CITES, B_FTP, offs, cnt, csr,
                  bP, out + (size_t)138000 * 128, N_PAPER, bid * 64);
  } else if (bid < NBP + NBA) {
    fused_body<3>(xbA, xbI, xbP, nullptr,
                  wt + 0 * 16384, wt + 5 * 16384, wt + 7 * 16384, nullptr,
                  B_ITA, B_PTA, 0, offs, cnt, csr,
                  bA, out, N_AUTHOR, (bid - NBP) * 64);
  } else if (bid < NBP + NBA + NBF) {
    fused_body<2>(xbF, xbP, nullptr, nullptr,
                  wt + 1 * 16384, wt + 9 * 16384, nullptr, nullptr,
                  B_TOPIC, 0, 0, offs, cnt, csr,
                  bF, out + (size_t)100000 * 128, N_FOS, (bid - NBP - NBA) * 64);
  } else {
    fused_body<2>(xbI, xbA, nullptr, nullptr,
                  wt + 2 * 16384, wt + 4 * 16384, nullptr, nullptr,
                  B_AFF, 0, 0, offs, cnt, csr,
                  bI, out + (size_t)130000 * 128, N_INST, (bid - NBP - NBA - NBF) * 64);
  }
}

// ---------------- fp32 fallback (small ws) ----------------------------------
typedef float4v f4;
__global__ __launch_bounds__(256, 4) void fb_gemm(
    const float* __restrict__ x0, const float* __restrict__ x1,
    const float* __restrict__ x2, const float* __restrict__ x3,
    const us* __restrict__ w0, const us* __restrict__ w1,
    const us* __restrict__ w2, const us* __restrict__ w3,
    int nsrc, int b1, int b2, int b3,
    const int* __restrict__ offs, const int* __restrict__ cnt,
    const int* __restrict__ csr,
    const float* __restrict__ bias, float* __restrict__ out, int n) {
  const int lane = threadIdx.x & 63;
  const int wv = threadIdx.x >> 6;
  const int rb = blockIdx.x * 64 + wv * 16;
  int ar = rb + (lane & 15); if (ar >= n) ar = n - 1;
  const int cw = (lane >> 4) * 8;
  const float* xs[4] = {x0, x1, x2, x3};
  const us* wsp[4] = {w0, w1, w2, w3};
  const int bases[4] = {0, b1, b2, b3};
  float4v acc[8];
  #pragma unroll
  for (int i = 0; i < 8; ++i) acc[i] = (float4v)0.0f;
  for (int kb = 0; kb < nsrc; ++kb) {
    short8v af[4];
    const float* xb = xs[kb];
    if (kb == 0) {
      const float* rp = xb + (size_t)ar * 128 + cw;
      #pragma unroll
      for (int ks = 0; ks < 4; ++ks) {
        f4 u = *(const f4*)(rp + ks * 32);
        f4 v = *(const f4*)(rp + ks * 32 + 4);
        af[ks] = pack8(u, v);
      }
    } else {
      int gd = bases[kb] + ar;
      int st = offs[gd];
      int deg = cnt[gd];
      f4 a0[4], a1[4];
      #pragma unroll
      for (int ks = 0; ks < 4; ++ks) { a0[ks] = (f4)0.f; a1[ks] = (f4)0.f; }
      for (int j = 0; j < deg; ++j) {
        int s0 = csr[st + j];
        const float* p0 = xb + (size_t)s0 * 128 + cw;
        #pragma unroll
        for (int ks = 0; ks < 4; ++ks) {
          a0[ks] += *(const f4*)(p0 + ks * 32);
          a1[ks] += *(const f4*)(p0 + ks * 32 + 4);
        }
      }
      float sc = 1.0f / (float)((deg > 0) ? deg : 1);
      #pragma unroll
      for (int ks = 0; ks < 4; ++ks)
        af[ks] = pack8(a0[ks] * sc, a1[ks] * sc);
    }
    const us* wb = wsp[kb] + (size_t)(lane & 15) * 128 + cw;
    #pragma unroll
    for (int ct = 0; ct < 8; ++ct) {
      short8v bfr[4];
      #pragma unroll
      for (int ks = 0; ks < 4; ++ks)
        bfr[ks] = *(const short8v*)(wb + ct * 2048 + ks * 32);
      #pragma unroll
      for (int ks = 0; ks < 4; ++ks)
        acc[ct] = __builtin_amdgcn_mfma_f32_16x16x32_bf16(af[ks], bfr[ks], acc[ct], 0, 0, 0);
    }
  }
  #pragma unroll
  for (int ct = 0; ct < 8; ++ct) {
    #pragma unroll
    for (int i = 0; i < 4; ++i) {
      int g = rb + (lane >> 4) * 4 + i;
      if (g < n) {
        int col = ct * 16 + (lane & 15);
        out[(size_t)g * 128 + col] = acc[ct][i] + bias[col];
      }
    }
  }
}

extern "C" void kernel_launch(void* const* d_in, const int* in_sizes, int n_in,
                              void* d_out, int out_size, void* d_ws, size_t ws_size,
                              hipStream_t stream) {
  const float* x_author = (const float*)d_in[0];
  const float* x_fos    = (const float*)d_in[1];
  const float* x_inst   = (const float*)d_in[2];
  const float* x_paper  = (const float*)d_in[3];

  Rels R;
  const int E[7]  = {150000, 150000, 500000, 500000, 1000000, 500000, 500000};
  const int ND[7] = {N_INST, N_AUTHOR, N_PAPER, N_AUTHOR, N_PAPER, N_FOS, N_PAPER};
  int base = 0;
  for (int r = 0; r < 7; ++r) {
    R.r[r].src = (const int*)d_in[4 + 2 * r];
    R.r[r].dst = (const int*)d_in[5 + 2 * r];
    R.r[r].E = E[r];
    R.r[r].base = base;
    base += ND[r];
  }

  char* ws = (char*)d_ws;
  int* cnt    = (int*)(ws + O_CNT);
  int* offs   = (int*)(ws + O_OFFS);
  int* cursor = (int*)(ws + O_CURSOR);
  int* btot   = (int*)(ws + O_BTOT);
  int* csr    = (int*)(ws + O_CSR);
  us* wt  = (us*)(ws + O_WT);
  us* xbA = (us*)(ws + XB_AUTHOR);
  us* xbF = (us*)(ws + XB_FOS);
  us* xbI = (us*)(ws + XB_INST);
  us* xbP = (us*)(ws + XB_PAPER);

  const int useBF = (ws_size >= WS_NEED_BF) ? 1 : 0;

  WPtrs WP;
  WP.w[0] = (const float*)d_in[18];
  WP.w[1] = (const float*)d_in[20];
  WP.w[2] = (const float*)d_in[22];
  WP.w[3] = (const float*)d_in[24];
  for (int r = 0; r < 7; ++r) WP.w[4 + r] = (const float*)d_in[26 + r];

  XCvt xcA = {x_author, xbA, N_AUTHOR * 16};
  XCvt xcF = {x_fos,    xbF, N_FOS * 16};
  XCvt xcI = {x_inst,   xbI, N_INST * 16};
  XCvt xcP = {x_paper,  xbP, N_PAPER * 16};

  hipMemsetAsync(cnt, 0, (size_t)NCNT * 4, stream);
  prep<<<2048, 256, 0, stream>>>(WP, wt, cnt, xcA, xcF, xcI, xcP, R, useBF);
  scan1<<<410, 256, 0, stream>>>(cnt, offs, btot, NCNT);
  scan23<<<1024, 512, 0, stream>>>(offs, cursor, btot, 410, NCNT);
  fill_k<<<2048, 256, 0, stream>>>(R, cursor, csr);

  float* out = (float*)d_out;
  const float* bA = (const float*)d_in[19];
  const float* bF = (const float*)d_in[21];
  const float* bI = (const float*)d_in[23];
  const float* bP = (const float*)d_in[25];

  if (useBF) {
    fused_all<<<NB_TOTAL, 256, 0, stream>>>(xbA, xbF, xbI, xbP, wt,
                                            offs, cnt, csr,
                                            bA, bF, bI, bP, out);
  } else {
    fb_gemm<<<NBA, 256, 0, stream>>>(
        x_author, x_inst, x_paper, nullptr,
        wt + 0 * 16384, wt + 5 * 16384, wt + 7 * 16384, nullptr,
        3, B_ITA, B_PTA, 0, offs, cnt, csr, bA, out, N_AUTHOR);
    fb_gemm<<<NBF, 256, 0, stream>>>(
        x_fos, x_paper, nullptr, nullptr,
        wt + 1 * 16384, wt + 9 * 16384, nullptr, nullptr,
        2, B_TOPIC, 0, 0, offs, cnt, csr, bF, out + (size_t)100000 * 128, N_FOS);
    fb_gemm<<<NBI, 256, 0, stream>>>(
        x_inst, x_author, nullptr, nullptr,
        wt + 2 * 16384, wt + 4 * 16384, nullptr, nullptr,
        2, B_AFF, 0, 0, offs, cnt, csr, bI, out + (size_t)130000 * 128, N_INST);
    fb_gemm<<<NBP, 256, 0, stream>>>(
        x_paper, x_author, x_paper, x_fos,
        wt + 3 * 16384, wt + 6 * 16384, wt + 8 * 16384, wt + 10 * 16384,
        4, B_WRITES, B_CITES, B_FTP, offs, cnt, csr, bP,
        out + (size_t)138000 * 128, N_PAPER);
  }
}

// Round 13
// 829.020 us; speedup vs baseline: 1.3426x; 1.0797x over previous
//
#include <hip/hip_runtime.h>

#define N_AUTHOR 100000
#define N_FOS    30000
#define N_INST   8000
#define N_PAPER  200000
#define NCNT     838000
#define ETOT     3300000
#define NSHARD   (NCNT / 8)   // 104750, exact

#define NBA 1563
#define NBF 469
#define NBI 125
#define NBP 3125
#define NB_TOTAL (NBP + NBA + NBF + NBI)

#define B_AFF    0
#define B_ITA    8000
#define B_WRITES 108000
#define B_PTA    308000
#define B_CITES  408000
#define B_TOPIC  608000
#define B_FTP    638000

typedef __attribute__((ext_vector_type(8))) short short8v;
typedef __attribute__((ext_vector_type(4))) float float4v;
typedef unsigned short us;

__device__ __forceinline__ us f2bf(float f) {
  unsigned u = __float_as_uint(f);
  u = u + 0x7fffu + ((u >> 16) & 1u);
  return (us)(u >> 16);
}
#define BF2F(s) __uint_as_float(((unsigned)(us)(s)) << 16)

__device__ __forceinline__ void acc8(float4v& x, float4v& y, short8v h) {
  x[0] += BF2F(h[0]); x[1] += BF2F(h[1]); x[2] += BF2F(h[2]); x[3] += BF2F(h[3]);
  y[0] += BF2F(h[4]); y[1] += BF2F(h[5]); y[2] += BF2F(h[6]); y[3] += BF2F(h[7]);
}

__device__ __forceinline__ short8v pack8(float4v a, float4v b) {
  short8v h;
  h[0] = (short)f2bf(a[0]); h[1] = (short)f2bf(a[1]);
  h[2] = (short)f2bf(a[2]); h[3] = (short)f2bf(a[3]);
  h[4] = (short)f2bf(b[0]); h[5] = (short)f2bf(b[1]);
  h[6] = (short)f2bf(b[2]); h[7] = (short)f2bf(b[3]);
  return h;
}

// ---------------- workspace layout (bytes) ----------------
#define O_CNT    0
#define O_OFFS   3352000
#define O_CURSOR 6704000
#define O_BTOT   10056000
#define O_CSR    10060096
#define O_WT     23260096
#define XB_AUTHOR 23620544
#define XB_FOS    49220544
#define XB_INST   56900544
#define XB_PAPER  58948544
#define WS_NEED_BF 110148544ULL

struct RelTab { const int* src; const int* dst; int E; int base; };
struct Rels { RelTab r[7]; };
struct WPtrs { const float* w[11]; };
struct XCvt { const float* x; us* xb; int n8; };

// prep: W transpose+bf16 and x fp32->bf16 (count moved to count_sh)
__global__ void prep(WPtrs P, us* __restrict__ wt,
                     XCvt x0, XCvt x1, XCvt x2, XCvt x3, int doX) {
  int gsz = gridDim.x * blockDim.x;
  int gtid = blockIdx.x * blockDim.x + threadIdx.x;
  for (int i = gtid; i < 11 * 16384; i += gsz) {
    int mat = i >> 14, rem = i & 16383;
    int k = rem >> 7, n = rem & 127;
    wt[mat * 16384 + n * 128 + k] = f2bf(P.w[mat][rem]);
  }
  if (doX) {
    XCvt xc[4] = {x0, x1, x2, x3};
    #pragma unroll
    for (int a = 0; a < 4; ++a) {
      const float* xp = xc[a].x;
      short8v* xbp = (short8v*)xc[a].xb;
      int n8 = xc[a].n8;
      for (int i = gtid; i < n8; i += gsz) {
        float4v v0 = *(const float4v*)(xp + (size_t)i * 8);
        float4v v1 = *(const float4v*)(xp + (size_t)i * 8 + 4);
        xbp[i] = pack8(v0, v1);
      }
    }
  }
}

// XCD-sharded edge counting: class cls handles dsts [cls*NSHARD, +NSHARD).
// cnt shard (0.4 MB) stays in the local XCD L2 -> atomics are L2-local.
__global__ __launch_bounds__(256, 8) void count_sh(Rels R, int* __restrict__ cnt) {
  const int cls = blockIdx.x & 7;
  const int lo = cls * NSHARD;
  const int hi = lo + NSHARD;
  const int gsz = (gridDim.x >> 3) * 256;
  const int gtid = (blockIdx.x >> 3) * 256 + threadIdx.x;
  #pragma unroll
  for (int rr = 0; rr < 7; ++rr) {
    const int* __restrict__ dst = R.r[rr].dst;
    const int E = R.r[rr].E, base = R.r[rr].base;
    for (int e = gtid; e < E; e += gsz) {
      int gd = base + dst[e];
      if (gd >= lo && gd < hi) atomicAdd(&cnt[gd], 1);
    }
  }
}

__global__ void scan1(const int* __restrict__ cnt, int* __restrict__ offs,
                      int* __restrict__ btot, int n) {
  __shared__ int sh[256];
  int tid = threadIdx.x;
  int base = blockIdx.x * 2048 + tid * 8;
  int v[8]; int s = 0;
  #pragma unroll
  for (int i = 0; i < 8; ++i) { v[i] = (base + i < n) ? cnt[base + i] : 0; s += v[i]; }
  sh[tid] = s; __syncthreads();
  for (int off = 1; off < 256; off <<= 1) {
    int t = (tid >= off) ? sh[tid - off] : 0;
    __syncthreads();
    sh[tid] += t;
    __syncthreads();
  }
  int excl = sh[tid] - s;
  if (tid == 255) btot[blockIdx.x] = sh[255];
  int run = excl;
  #pragma unroll
  for (int i = 0; i < 8; ++i) { if (base + i < n) offs[base + i] = run; run += v[i]; }
}

__global__ void scan23(int* __restrict__ offs, int* __restrict__ cursor,
                       const int* __restrict__ btot, int nb, int n) {
  __shared__ int sh[512];
  int tid = threadIdx.x;
  int v = (tid < nb) ? btot[tid] : 0;
  sh[tid] = v; __syncthreads();
  for (int off = 1; off < 512; off <<= 1) {
    int t = (tid >= off) ? sh[tid - off] : 0;
    __syncthreads();
    sh[tid] += t;
    __syncthreads();
  }
  int excl = sh[tid] - v;
  __syncthreads();
  sh[tid] = excl;
  __syncthreads();
  int gsz = gridDim.x * 512;
  for (int idx = blockIdx.x * 512 + tid; idx < n; idx += gsz) {
    int val = offs[idx] + sh[idx >> 11];
    offs[idx] = val;
    cursor[idx] = val;
  }
}

// XCD-sharded CSR fill: per class, cursor shard (0.4 MB) + csr shard
// (~1.65 MB contiguous, since offs is monotone) fit the local 4 MB L2 ->
// csr lines merge fully before eviction (kills the 16x write amp).
__global__ __launch_bounds__(256, 8) void fill_sh(Rels R, int* __restrict__ cursor,
                                                  int* __restrict__ csr) {
  const int cls = blockIdx.x & 7;
  const int lo = cls * NSHARD;
  const int hi = lo + NSHARD;
  const int gsz = (gridDim.x >> 3) * 256;
  const int gtid = (blockIdx.x >> 3) * 256 + threadIdx.x;
  #pragma unroll
  for (int rr = 0; rr < 7; ++rr) {
    const int* __restrict__ src = R.r[rr].src;
    const int* __restrict__ dst = R.r[rr].dst;
    const int E = R.r[rr].E, base = R.r[rr].base;
    for (int e = gtid; e < E; e += gsz) {
      int gd = base + dst[e];
      if (gd >= lo && gd < hi) {
        int p = atomicAdd(&cursor[gd], 1);
        csr[p] = src[e];
      }
    }
  }
}

// ---------------- fused gather-GEMM body (2-edge batching) ------------------
template <int NSRC>
__device__ __forceinline__ void fused_body(
    const us* __restrict__ x0, const us* __restrict__ x1,
    const us* __restrict__ x2, const us* __restrict__ x3,
    const us* __restrict__ w0, const us* __restrict__ w1,
    const us* __restrict__ w2, const us* __restrict__ w3,
    int b1, int b2, int b3,
    const int* __restrict__ offs, const int* __restrict__ cnt,
    const int* __restrict__ csr,
    const float* __restrict__ bias, float* __restrict__ out, int n, int rb0) {
  const int lane = threadIdx.x & 63;
  const int wv = threadIdx.x >> 6;
  const int rb = rb0 + wv * 16;
  int ar = rb + (lane & 15); if (ar >= n) ar = n - 1;
  const int cw = (lane >> 4) * 8;

  const us* xs[4] = {x0, x1, x2, x3};
  const us* wsp[4] = {w0, w1, w2, w3};
  const int bases[4] = {0, b1, b2, b3};

  float4v acc[8];
  #pragma unroll
  for (int i = 0; i < 8; ++i) acc[i] = (float4v)0.0f;

  #pragma unroll
  for (int kb = 0; kb < NSRC; ++kb) {
    short8v af[4];
    if (kb == 0) {
      const us* rp = xs[0] + (size_t)ar * 128 + cw;
      #pragma unroll
      for (int ks = 0; ks < 4; ++ks)
        af[ks] = *(const short8v*)(rp + ks * 32);
    } else {
      int gd = bases[kb] + ar;
      int st = offs[gd];
      int deg = cnt[gd];
      const us* xb = xs[kb];
      float4v a0[4], a1[4];
      #pragma unroll
      for (int ks = 0; ks < 4; ++ks) { a0[ks] = (float4v)0.f; a1[ks] = (float4v)0.f; }
      int j = 0;
      for (; j + 2 <= deg; j += 2) {
        int s0 = csr[st + j], s1 = csr[st + j + 1];
        const us* p0 = xb + (size_t)s0 * 128 + cw;
        const us* p1 = xb + (size_t)s1 * 128 + cw;
        #pragma unroll
        for (int ks = 0; ks < 4; ++ks) {
          short8v h0 = *(const short8v*)(p0 + ks * 32);
          short8v h1 = *(const short8v*)(p1 + ks * 32);
          acc8(a0[ks], a1[ks], h0);
          acc8(a0[ks], a1[ks], h1);
        }
      }
      if (j < deg) {
        int s0 = csr[st + j];
        const us* p0 = xb + (size_t)s0 * 128 + cw;
        #pragma unroll
        for (int ks = 0; ks < 4; ++ks) {
          short8v h0 = *(const short8v*)(p0 + ks * 32);
          acc8(a0[ks], a1[ks], h0);
        }
      }
      float sc = 1.0f / (float)((deg > 0) ? deg : 1);
      #pragma unroll
      for (int ks = 0; ks < 4; ++ks)
        af[ks] = pack8(a0[ks] * sc, a1[ks] * sc);
    }
    const us* wb = wsp[kb] + (size_t)(lane & 15) * 128 + cw;
    #pragma unroll
    for (int ct = 0; ct < 8; ++ct) {
      short8v bfr[4];
      #pragma unroll
      for (int ks = 0; ks < 4; ++ks)
        bfr[ks] = *(const short8v*)(wb + ct * 2048 + ks * 32);
      #pragma unroll
      for (int ks = 0; ks < 4; ++ks)
        acc[ct] = __builtin_amdgcn_mfma_f32_16x16x32_bf16(af[ks], bfr[ks], acc[ct], 0, 0, 0);
    }
  }
  #pragma unroll
  for (int ct = 0; ct < 8; ++ct) {
    #pragma unroll
    for (int i = 0; i < 4; ++i) {
      int g = rb + (lane >> 4) * 4 + i;
      if (g < n) {
        int col = ct * 16 + (lane & 15);
        out[(size_t)g * 128 + col] = acc[ct][i] + bias[col];
      }
    }
  }
}

__global__ __launch_bounds__(256, 6) void fused_all(
    const us* __restrict__ xbA, const us* __restrict__ xbF,
    const us* __restrict__ xbI, const us* __restrict__ xbP,
    const us* __restrict__ wt,
    const int* __restrict__ offs, const int* __restrict__ cnt,
    const int* __restrict__ csr,
    const float* __restrict__ bA, const float* __restrict__ bF,
    const float* __restrict__ bI, const float* __restrict__ bP,
    float* __restrict__ out) {
  const int bid = blockIdx.x;
  if (bid < NBP) {
    fused_body<4>(xbP, xbA, xbP, xbF,
                  wt + 3 * 16384, wt + 6 * 16384, wt + 8 * 16384, wt + 10 * 16384,
                  B_WRITES, B_CITES, B_FTP, offs, cnt, csr,
                  bP, out + (size_t)138000 * 128, N_PAPER, bid * 64);
  } else if (bid < NBP + NBA) {
    fused_body<3>(xbA, xbI, xbP, nullptr,
                  wt + 0 * 16384, wt + 5 * 16384, wt + 7 * 16384, nullptr,
                  B_ITA, B_PTA, 0, offs, cnt, csr,
                  bA, out, N_AUTHOR, (bid - NBP) * 64);
  } else if (bid < NBP + NBA + NBF) {
    fused_body<2>(xbF, xbP, nullptr, nullptr,
                  wt + 1 * 16384, wt + 9 * 16384, nullptr, nullptr,
                  B_TOPIC, 0, 0, offs, cnt, csr,
                  bF, out + (size_t)100000 * 128, N_FOS, (bid - NBP - NBA) * 64);
  } else {
    fused_body<2>(xbI, xbA, nullptr, nullptr,
                  wt + 2 * 16384, wt + 4 * 16384, nullptr, nullptr,
                  B_AFF, 0, 0, offs, cnt, csr,
                  bI, out + (size_t)130000 * 128, N_INST, (bid - NBP - NBA - NBF) * 64);
  }
}

// ---------------- fp32 fallback (small ws) ----------------------------------
typedef float4v f4;
__global__ __launch_bounds__(256, 4) void fb_gemm(
    const float* __restrict__ x0, const float* __restrict__ x1,
    const float* __restrict__ x2, const float* __restrict__ x3,
    const us* __restrict__ w0, const us* __restrict__ w1,
    const us* __restrict__ w2, const us* __restrict__ w3,
    int nsrc, int b1, int b2, int b3,
    const int* __restrict__ offs, const int* __restrict__ cnt,
    const int* __restrict__ csr,
    const float* __restrict__ bias, float* __restrict__ out, int n) {
  const int lane = threadIdx.x & 63;
  const int wv = threadIdx.x >> 6;
  const int rb = blockIdx.x * 64 + wv * 16;
  int ar = rb + (lane & 15); if (ar >= n) ar = n - 1;
  const int cw = (lane >> 4) * 8;
  const float* xs[4] = {x0, x1, x2, x3};
  const us* wsp[4] = {w0, w1, w2, w3};
  const int bases[4] = {0, b1, b2, b3};
  float4v acc[8];
  #pragma unroll
  for (int i = 0; i < 8; ++i) acc[i] = (float4v)0.0f;
  for (int kb = 0; kb < nsrc; ++kb) {
    short8v af[4];
    const float* xb = xs[kb];
    if (kb == 0) {
      const float* rp = xb + (size_t)ar * 128 + cw;
      #pragma unroll
      for (int ks = 0; ks < 4; ++ks) {
        f4 u = *(const f4*)(rp + ks * 32);
        f4 v = *(const f4*)(rp + ks * 32 + 4);
        af[ks] = pack8(u, v);
      }
    } else {
      int gd = bases[kb] + ar;
      int st = offs[gd];
      int deg = cnt[gd];
      f4 a0[4], a1[4];
      #pragma unroll
      for (int ks = 0; ks < 4; ++ks) { a0[ks] = (f4)0.f; a1[ks] = (f4)0.f; }
      for (int j = 0; j < deg; ++j) {
        int s0 = csr[st + j];
        const float* p0 = xb + (size_t)s0 * 128 + cw;
        #pragma unroll
        for (int ks = 0; ks < 4; ++ks) {
          a0[ks] += *(const f4*)(p0 + ks * 32);
          a1[ks] += *(const f4*)(p0 + ks * 32 + 4);
        }
      }
      float sc = 1.0f / (float)((deg > 0) ? deg : 1);
      #pragma unroll
      for (int ks = 0; ks < 4; ++ks)
        af[ks] = pack8(a0[ks] * sc, a1[ks] * sc);
    }
    const us* wb = wsp[kb] + (size_t)(lane & 15) * 128 + cw;
    #pragma unroll
    for (int ct = 0; ct < 8; ++ct) {
      short8v bfr[4];
      #pragma unroll
      for (int ks = 0; ks < 4; ++ks)
        bfr[ks] = *(const short8v*)(wb + ct * 2048 + ks * 32);
      #pragma unroll
      for (int ks = 0; ks < 4; ++ks)
        acc[ct] = __builtin_amdgcn_mfma_f32_16x16x32_bf16(af[ks], bfr[ks], acc[ct], 0, 0, 0);
    }
  }
  #pragma unroll
  for (int ct = 0; ct < 8; ++ct) {
    #pragma unroll
    for (int i = 0; i < 4; ++i) {
      int g = rb + (lane >> 4) * 4 + i;
      if (g < n) {
        int col = ct * 16 + (lane & 15);
        out[(size_t)g * 128 + col] = acc[ct][i] + bias[col];
      }
    }
  }
}

extern "C" void kernel_launch(void* const* d_in, const int* in_sizes, int n_in,
                              void* d_out, int out_size, void* d_ws, size_t ws_size,
                              hipStream_t stream) {
  const float* x_author = (const float*)d_in[0];
  const float* x_fos    = (const float*)d_in[1];
  const float* x_inst   = (const float*)d_in[2];
  const float* x_paper  = (const float*)d_in[3];

  Rels R;
  const int E[7]  = {150000, 150000, 500000, 500000, 1000000, 500000, 500000};
  const int ND[7] = {N_INST, N_AUTHOR, N_PAPER, N_AUTHOR, N_PAPER, N_FOS, N_PAPER};
  int base = 0;
  for (int r = 0; r < 7; ++r) {
    R.r[r].src = (const int*)d_in[4 + 2 * r];
    R.r[r].dst = (const int*)d_in[5 + 2 * r];
    R.r[r].E = E[r];
    R.r[r].base = base;
    base += ND[r];
  }

  char* ws = (char*)d_ws;
  int* cnt    = (int*)(ws + O_CNT);
  int* offs   = (int*)(ws + O_OFFS);
  int* cursor = (int*)(ws + O_CURSOR);
  int* btot   = (int*)(ws + O_BTOT);
  int* csr    = (int*)(ws + O_CSR);
  us* wt  = (us*)(ws + O_WT);
  us* xbA = (us*)(ws + XB_AUTHOR);
  us* xbF = (us*)(ws + XB_FOS);
  us* xbI = (us*)(ws + XB_INST);
  us* xbP = (us*)(ws + XB_PAPER);

  const int useBF = (ws_size >= WS_NEED_BF) ? 1 : 0;

  WPtrs WP;
  WP.w[0] = (const float*)d_in[18];
  WP.w[1] = (const float*)d_in[20];
  WP.w[2] = (const float*)d_in[22];
  WP.w[3] = (const float*)d_in[24];
  for (int r = 0; r < 7; ++r) WP.w[4 + r] = (const float*)d_in[26 + r];

  XCvt xcA = {x_author, xbA, N_AUTHOR * 16};
  XCvt xcF = {x_fos,    xbF, N_FOS * 16};
  XCvt xcI = {x_inst,   xbI, N_INST * 16};
  XCvt xcP = {x_paper,  xbP, N_PAPER * 16};

  hipMemsetAsync(cnt, 0, (size_t)NCNT * 4, stream);
  prep<<<2048, 256, 0, stream>>>(WP, wt, xcA, xcF, xcI, xcP, useBF);
  count_sh<<<2048, 256, 0, stream>>>(R, cnt);
  scan1<<<410, 256, 0, stream>>>(cnt, offs, btot, NCNT);
  scan23<<<1024, 512, 0, stream>>>(offs, cursor, btot, 410, NCNT);
  fill_sh<<<2048, 256, 0, stream>>>(R, cursor, csr);

  float* out = (float*)d_out;
  const float* bA = (const float*)d_in[19];
  const float* bF = (const float*)d_in[21];
  const float* bI = (const float*)d_in[23];
  const float* bP = (const float*)d_in[25];

  if (useBF) {
    fused_all<<<NB_TOTAL, 256, 0, stream>>>(xbA, xbF, xbI, xbP, wt,
                                            offs, cnt, csr,
                                            bA, bF, bI, bP, out);
  } else {
    fb_gemm<<<NBA, 256, 0, stream>>>(
        x_author, x_inst, x_paper, nullptr,
        wt + 0 * 16384, wt + 5 * 16384, wt + 7 * 16384, nullptr,
        3, B_ITA, B_PTA, 0, offs, cnt, csr, bA, out, N_AUTHOR);
    fb_gemm<<<NBF, 256, 0, stream>>>(
        x_fos, x_paper, nullptr, nullptr,
        wt + 1 * 16384, wt + 9 * 16384, nullptr, nullptr,
        2, B_TOPIC, 0, 0, offs, cnt, csr, bF, out + (size_t)100000 * 128, N_FOS);
    fb_gemm<<<NBI, 256, 0, stream>>>(
        x_inst, x_author, nullptr, nullptr,
        wt + 2 * 16384, wt + 4 * 16384, nullptr, nullptr,
        2, B_AFF, 0, 0, offs, cnt, csr, bI, out + (size_t)130000 * 128, N_INST);
    fb_gemm<<<NBP, 256, 0, stream>>>(
        x_paper, x_author, x_paper, x_fos,
        wt + 3 * 16384, wt + 6 * 16384, wt + 8 * 16384, wt + 10 * 16384,
        4, B_WRITES, B_CITES, B_FTP, offs, cnt, csr, bP,
        out + (size_t)138000 * 128, N_PAPER);
  }
}

// Round 14
// 825.405 us; speedup vs baseline: 1.3484x; 1.0044x over previous
//
#include <hip/hip_runtime.h>

#define N_AUTHOR 100000
#define N_FOS    30000
#define N_INST   8000
#define N_PAPER  200000
#define NCNT     838000
#define ETOT     3300000
#define NSHARD   (NCNT / 8)   // 104750, exact

#define NBA 1563
#define NBF 469
#define NBI 125
#define NBP 3125
#define NB_TOTAL (NBP + NBA + NBF + NBI)

#define B_AFF    0
#define B_ITA    8000
#define B_WRITES 108000
#define B_PTA    308000
#define B_CITES  408000
#define B_TOPIC  608000
#define B_FTP    638000

typedef __attribute__((ext_vector_type(8))) short short8v;
typedef __attribute__((ext_vector_type(4))) float float4v;
typedef unsigned short us;

__device__ __forceinline__ us f2bf(float f) {
  unsigned u = __float_as_uint(f);
  u = u + 0x7fffu + ((u >> 16) & 1u);
  return (us)(u >> 16);
}
#define BF2F(s) __uint_as_float(((unsigned)(us)(s)) << 16)

__device__ __forceinline__ void acc8(float4v& x, float4v& y, short8v h) {
  x[0] += BF2F(h[0]); x[1] += BF2F(h[1]); x[2] += BF2F(h[2]); x[3] += BF2F(h[3]);
  y[0] += BF2F(h[4]); y[1] += BF2F(h[5]); y[2] += BF2F(h[6]); y[3] += BF2F(h[7]);
}

__device__ __forceinline__ short8v pack8(float4v a, float4v b) {
  short8v h;
  h[0] = (short)f2bf(a[0]); h[1] = (short)f2bf(a[1]);
  h[2] = (short)f2bf(a[2]); h[3] = (short)f2bf(a[3]);
  h[4] = (short)f2bf(b[0]); h[5] = (short)f2bf(b[1]);
  h[6] = (short)f2bf(b[2]); h[7] = (short)f2bf(b[3]);
  return h;
}

// ---------------- workspace layout (bytes) ----------------
#define O_CNT    0
#define O_OFFS   3352000
#define O_CURSOR 6704000
#define O_BTOT   10056000
#define O_CSR    10060096
#define O_WT     23260096
#define XB_AUTHOR 23620544
#define XB_FOS    49220544
#define XB_INST   56900544
#define XB_PAPER  58948544
#define WS_NEED_BF 110148544ULL

struct RelTab { const int* src; const int* dst; int E; int base; };
struct Rels { RelTab r[7]; };
struct WPtrs { const float* w[11]; };
struct XCvt { const float* x; us* xb; int n8; };

// prep: W transpose+bf16, x fp32->bf16, PLUS XCD-sharded edge counting.
__global__ __launch_bounds__(256, 8) void prep(WPtrs P, us* __restrict__ wt,
                     int* __restrict__ cnt,
                     XCvt x0, XCvt x1, XCvt x2, XCvt x3,
                     Rels R, int doX) {
  int gsz = gridDim.x * blockDim.x;
  int gtid = blockIdx.x * blockDim.x + threadIdx.x;
  for (int i = gtid; i < 11 * 16384; i += gsz) {
    int mat = i >> 14, rem = i & 16383;
    int k = rem >> 7, n = rem & 127;
    wt[mat * 16384 + n * 128 + k] = f2bf(P.w[mat][rem]);
  }
  if (doX) {
    XCvt xc[4] = {x0, x1, x2, x3};
    #pragma unroll
    for (int a = 0; a < 4; ++a) {
      const float* xp = xc[a].x;
      short8v* xbp = (short8v*)xc[a].xb;
      int n8 = xc[a].n8;
      for (int i = gtid; i < n8; i += gsz) {
        float4v v0 = *(const float4v*)(xp + (size_t)i * 8);
        float4v v1 = *(const float4v*)(xp + (size_t)i * 8 + 4);
        xbp[i] = pack8(v0, v1);
      }
    }
  }
  const int cls = blockIdx.x & 7;
  const int lo = cls * NSHARD;
  const int hi = lo + NSHARD;
  const int sgsz = (gridDim.x >> 3) * 256;
  const int sgtid = (blockIdx.x >> 3) * 256 + threadIdx.x;
  #pragma unroll
  for (int rr = 0; rr < 7; ++rr) {
    const int* __restrict__ dst = R.r[rr].dst;
    const int E = R.r[rr].E, base = R.r[rr].base;
    for (int e = sgtid; e < E; e += sgsz) {
      int gd = base + dst[e];
      if (gd >= lo && gd < hi) atomicAdd(&cnt[gd], 1);
    }
  }
}

__global__ void scan1(const int* __restrict__ cnt, int* __restrict__ offs,
                      int* __restrict__ btot, int n) {
  __shared__ int sh[256];
  int tid = threadIdx.x;
  int base = blockIdx.x * 2048 + tid * 8;
  int v[8]; int s = 0;
  #pragma unroll
  for (int i = 0; i < 8; ++i) { v[i] = (base + i < n) ? cnt[base + i] : 0; s += v[i]; }
  sh[tid] = s; __syncthreads();
  for (int off = 1; off < 256; off <<= 1) {
    int t = (tid >= off) ? sh[tid - off] : 0;
    __syncthreads();
    sh[tid] += t;
    __syncthreads();
  }
  int excl = sh[tid] - s;
  if (tid == 255) btot[blockIdx.x] = sh[255];
  int run = excl;
  #pragma unroll
  for (int i = 0; i < 8; ++i) { if (base + i < n) offs[base + i] = run; run += v[i]; }
}

__global__ void scan23(int* __restrict__ offs, int* __restrict__ cursor,
                       const int* __restrict__ btot, int nb, int n) {
  __shared__ int sh[512];
  int tid = threadIdx.x;
  int v = (tid < nb) ? btot[tid] : 0;
  sh[tid] = v; __syncthreads();
  for (int off = 1; off < 512; off <<= 1) {
    int t = (tid >= off) ? sh[tid - off] : 0;
    __syncthreads();
    sh[tid] += t;
    __syncthreads();
  }
  int excl = sh[tid] - v;
  __syncthreads();
  sh[tid] = excl;
  __syncthreads();
  int gsz = gridDim.x * 512;
  for (int idx = blockIdx.x * 512 + tid; idx < n; idx += gsz) {
    int val = offs[idx] + sh[idx >> 11];
    offs[idx] = val;
    cursor[idx] = val;
  }
}

__global__ __launch_bounds__(256, 8) void fill_sh(Rels R, int* __restrict__ cursor,
                                                  int* __restrict__ csr) {
  const int cls = blockIdx.x & 7;
  const int lo = cls * NSHARD;
  const int hi = lo + NSHARD;
  const int gsz = (gridDim.x >> 3) * 256;
  const int gtid = (blockIdx.x >> 3) * 256 + threadIdx.x;
  #pragma unroll
  for (int rr = 0; rr < 7; ++rr) {
    const int* __restrict__ src = R.r[rr].src;
    const int* __restrict__ dst = R.r[rr].dst;
    const int E = R.r[rr].E, base = R.r[rr].base;
    for (int e = gtid; e < E; e += gsz) {
      int gd = base + dst[e];
      if (gd >= lo && gd < hi) {
        int p = atomicAdd(&cursor[gd], 1);
        csr[p] = src[e];
      }
    }
  }
}

// ---------------- fused gather-GEMM body (4-edge batching) ------------------
template <int NSRC>
__device__ __forceinline__ void fused_body(
    const us* __restrict__ x0, const us* __restrict__ x1,
    const us* __restrict__ x2, const us* __restrict__ x3,
    const us* __restrict__ w0, const us* __restrict__ w1,
    const us* __restrict__ w2, const us* __restrict__ w3,
    int b1, int b2, int b3,
    const int* __restrict__ offs, const int* __restrict__ cnt,
    const int* __restrict__ csr,
    const float* __restrict__ bias, float* __restrict__ out, int n, int rb0) {
  const int lane = threadIdx.x & 63;
  const int wv = threadIdx.x >> 6;
  const int rb = rb0 + wv * 16;
  int ar = rb + (lane & 15); if (ar >= n) ar = n - 1;
  const int cw = (lane >> 4) * 8;

  const us* xs[4] = {x0, x1, x2, x3};
  const us* wsp[4] = {w0, w1, w2, w3};
  const int bases[4] = {0, b1, b2, b3};

  float4v acc[8];
  #pragma unroll
  for (int i = 0; i < 8; ++i) acc[i] = (float4v)0.0f;

  #pragma unroll
  for (int kb = 0; kb < NSRC; ++kb) {
    short8v af[4];
    if (kb == 0) {
      const us* rp = xs[0] + (size_t)ar * 128 + cw;
      #pragma unroll
      for (int ks = 0; ks < 4; ++ks)
        af[ks] = *(const short8v*)(rp + ks * 32);
    } else {
      int gd = bases[kb] + ar;
      int st = offs[gd];
      int deg = cnt[gd];
      const us* xb = xs[kb];
      float4v a0[4], a1[4];
      #pragma unroll
      for (int ks = 0; ks < 4; ++ks) { a0[ks] = (float4v)0.f; a1[ks] = (float4v)0.f; }
      int j = 0;
      for (; j + 4 <= deg; j += 4) {
        int s0 = csr[st + j],     s1 = csr[st + j + 1];
        int s2 = csr[st + j + 2], s3 = csr[st + j + 3];
        const us* p0 = xb + (size_t)s0 * 128 + cw;
        const us* p1 = xb + (size_t)s1 * 128 + cw;
        const us* p2 = xb + (size_t)s2 * 128 + cw;
        const us* p3 = xb + (size_t)s3 * 128 + cw;
        #pragma unroll
        for (int ks = 0; ks < 4; ++ks) {
          short8v h0 = *(const short8v*)(p0 + ks * 32);
          short8v h1 = *(const short8v*)(p1 + ks * 32);
          short8v h2 = *(const short8v*)(p2 + ks * 32);
          short8v h3 = *(const short8v*)(p3 + ks * 32);
          acc8(a0[ks], a1[ks], h0);
          acc8(a0[ks], a1[ks], h1);
          acc8(a0[ks], a1[ks], h2);
          acc8(a0[ks], a1[ks], h3);
        }
      }
      for (; j < deg; ++j) {
        int s0 = csr[st + j];
        const us* p0 = xb + (size_t)s0 * 128 + cw;
        #pragma unroll
        for (int ks = 0; ks < 4; ++ks) {
          short8v h0 = *(const short8v*)(p0 + ks * 32);
          acc8(a0[ks], a1[ks], h0);
        }
      }
      float sc = 1.0f / (float)((deg > 0) ? deg : 1);
      #pragma unroll
      for (int ks = 0; ks < 4; ++ks)
        af[ks] = pack8(a0[ks] * sc, a1[ks] * sc);
    }
    const us* wb = wsp[kb] + (size_t)(lane & 15) * 128 + cw;
    #pragma unroll
    for (int ct = 0; ct < 8; ++ct) {
      short8v bfr[4];
      #pragma unroll
      for (int ks = 0; ks < 4; ++ks)
        bfr[ks] = *(const short8v*)(wb + ct * 2048 + ks * 32);
      #pragma unroll
      for (int ks = 0; ks < 4; ++ks)
        acc[ct] = __builtin_amdgcn_mfma_f32_16x16x32_bf16(af[ks], bfr[ks], acc[ct], 0, 0, 0);
    }
  }
  #pragma unroll
  for (int ct = 0; ct < 8; ++ct) {
    #pragma unroll
    for (int i = 0; i < 4; ++i) {
      int g = rb + (lane >> 4) * 4 + i;
      if (g < n) {
        int col = ct * 16 + (lane & 15);
        out[(size_t)g * 128 + col] = acc[ct][i] + bias[col];
      }
    }
  }
}

__global__ __launch_bounds__(256, 6) void fused_all(
    const us* __restrict__ xbA, const us* __restrict__ xbF,
    const us* __restrict__ xbI, const us* __restrict__ xbP,
    const us* __restrict__ wt,
    const int* __restrict__ offs, const int* __restrict__ cnt,
    const int* __restrict__ csr,
    const float* __restrict__ bA, const float* __restrict__ bF,
    const float* __restrict__ bI, const float* __restrict__ bP,
    float* __restrict__ out) {
  const int bid = blockIdx.x;
  if (bid < NBP) {
    fused_body<4>(xbP, xbA, xbP, xbF,
                  wt + 3 * 16384, wt + 6 * 16384, wt + 8 * 16384, wt + 10 * 16384,
                  B_WRITES, B_CITES, B_FTP, offs, cnt, csr,
                  bP, out + (size_t)138000 * 128, N_PAPER, bid * 64);
  } else if (bid < NBP + NBA) {
    fused_body<3>(xbA, xbI, xbP, nullptr,
                  wt + 0 * 16384, wt + 5 * 16384, wt + 7 * 16384, nullptr,
                  B_ITA, B_PTA, 0, offs, cnt, csr,
                  bA, out, N_AUTHOR, (bid - NBP) * 64);
  } else if (bid < NBP + NBA + NBF) {
    fused_body<2>(xbF, xbP, nullptr, nullptr,
                  wt + 1 * 16384, wt + 9 * 16384, nullptr, nullptr,
                  B_TOPIC, 0, 0, offs, cnt, csr,
                  bF, out + (size_t)100000 * 128, N_FOS, (bid - NBP - NBA) * 64);
  } else {
    fused_body<2>(xbI, xbA, nullptr, nullptr,
                  wt + 2 * 16384, wt + 4 * 16384, nullptr, nullptr,
                  B_AFF, 0, 0, offs, cnt, csr,
                  bI, out + (size_t)130000 * 128, N_INST, (bid - NBP - NBA - NBF) * 64);
  }
}

// ---------------- fp32 fallback (small ws) ----------------------------------
typedef float4v f4;
__global__ __launch_bounds__(256, 4) void fb_gemm(
    const float* __restrict__ x0, const float* __restrict__ x1,
    const float* __restrict__ x2, const float* __restrict__ x3,
    const us* __restrict__ w0, const us* __restrict__ w1,
    const us* __restrict__ w2, const us* __restrict__ w3,
    int nsrc, int b1, int b2, int b3,
    const int* __restrict__ offs, const int* __restrict__ cnt,
    const int* __restrict__ csr,
    const float* __restrict__ bias, float* __restrict__ out, int n) {
  const int lane = threadIdx.x & 63;
  const int wv = threadIdx.x >> 6;
  const int rb = blockIdx.x * 64 + wv * 16;
  int ar = rb + (lane & 15); if (ar >= n) ar = n - 1;
  const int cw = (lane >> 4) * 8;
  const float* xs[4] = {x0, x1, x2, x3};
  const us* wsp[4] = {w0, w1, w2, w3};
  const int bases[4] = {0, b1, b2, b3};
  float4v acc[8];
  #pragma unroll
  for (int i = 0; i < 8; ++i) acc[i] = (float4v)0.0f;
  for (int kb = 0; kb < nsrc; ++kb) {
    short8v af[4];
    const float* xb = xs[kb];
    if (kb == 0) {
      const float* rp = xb + (size_t)ar * 128 + cw;
      #pragma unroll
      for (int ks = 0; ks < 4; ++ks) {
        f4 u = *(const f4*)(rp + ks * 32);
        f4 v = *(const f4*)(rp + ks * 32 + 4);
        af[ks] = pack8(u, v);
      }
    } else {
      int gd = bases[kb] + ar;
      int st = offs[gd];
      int deg = cnt[gd];
      f4 a0[4], a1[4];
      #pragma unroll
      for (int ks = 0; ks < 4; ++ks) { a0[ks] = (f4)0.f; a1[ks] = (f4)0.f; }
      for (int j = 0; j < deg; ++j) {
        int s0 = csr[st + j];
        const float* p0 = xb + (size_t)s0 * 128 + cw;
        #pragma unroll
        for (int ks = 0; ks < 4; ++ks) {
          a0[ks] += *(const f4*)(p0 + ks * 32);
          a1[ks] += *(const f4*)(p0 + ks * 32 + 4);
        }
      }
      float sc = 1.0f / (float)((deg > 0) ? deg : 1);
      #pragma unroll
      for (int ks = 0; ks < 4; ++ks)
        af[ks] = pack8(a0[ks] * sc, a1[ks] * sc);
    }
    const us* wb = wsp[kb] + (size_t)(lane & 15) * 128 + cw;
    #pragma unroll
    for (int ct = 0; ct < 8; ++ct) {
      short8v bfr[4];
      #pragma unroll
      for (int ks = 0; ks < 4; ++ks)
        bfr[ks] = *(const short8v*)(wb + ct * 2048 + ks * 32);
      #pragma unroll
      for (int ks = 0; ks < 4; ++ks)
        acc[ct] = __builtin_amdgcn_mfma_f32_16x16x32_bf16(af[ks], bfr[ks], acc[ct], 0, 0, 0);
    }
  }
  #pragma unroll
  for (int ct = 0; ct < 8; ++ct) {
    #pragma unroll
    for (int i = 0; i < 4; ++i) {
      int g = rb + (lane >> 4) * 4 + i;
      if (g < n) {
        int col = ct * 16 + (lane & 15);
        out[(size_t)g * 128 + col] = acc[ct][i] + bias[col];
      }
    }
  }
}

extern "C" void kernel_launch(void* const* d_in, const int* in_sizes, int n_in,
                              void* d_out, int out_size, void* d_ws, size_t ws_size,
                              hipStream_t stream) {
  const float* x_author = (const float*)d_in[0];
  const float* x_fos    = (const float*)d_in[1];
  const float* x_inst   = (const float*)d_in[2];
  const float* x_paper  = (const float*)d_in[3];

  Rels R;
  const int E[7]  = {150000, 150000, 500000, 500000, 1000000, 500000, 500000};
  const int ND[7] = {N_INST, N_AUTHOR, N_PAPER, N_AUTHOR, N_PAPER, N_FOS, N_PAPER};
  int base = 0;
  for (int r = 0; r < 7; ++r) {
    R.r[r].src = (const int*)d_in[4 + 2 * r];
    R.r[r].dst = (const int*)d_in[5 + 2 * r];
    R.r[r].E = E[r];
    R.r[r].base = base;
    base += ND[r];
  }

  char* ws = (char*)d_ws;
  int* cnt    = (int*)(ws + O_CNT);
  int* offs   = (int*)(ws + O_OFFS);
  int* cursor = (int*)(ws + O_CURSOR);
  int* btot   = (int*)(ws + O_BTOT);
  int* csr    = (int*)(ws + O_CSR);
  us* wt  = (us*)(ws + O_WT);
  us* xbA = (us*)(ws + XB_AUTHOR);
  us* xbF = (us*)(ws + XB_FOS);
  us* xbI = (us*)(ws + XB_INST);
  us* xbP = (us*)(ws + XB_PAPER);

  const int useBF = (ws_size >= WS_NEED_BF) ? 1 : 0;

  WPtrs WP;
  WP.w[0] = (const float*)d_in[18];
  WP.w[1] = (const float*)d_in[20];
  WP.w[2] = (const float*)d_in[22];
  WP.w[3] = (const float*)d_in[24];
  for (int r = 0; r < 7; ++r) WP.w[4 + r] = (const float*)d_in[26 + r];

  XCvt xcA = {x_author, xbA, N_AUTHOR * 16};
  XCvt xcF = {x_fos,    xbF, N_FOS * 16};
  XCvt xcI = {x_inst,   xbI, N_INST * 16};
  XCvt xcP = {x_paper,  xbP, N_PAPER * 16};

  hipMemsetAsync(cnt, 0, (size_t)NCNT * 4, stream);
  prep<<<2048, 256, 0, stream>>>(WP, wt, cnt, xcA, xcF, xcI, xcP, R, useBF);
  scan1<<<410, 256, 0, stream>>>(cnt, offs, btot, NCNT);
  scan23<<<1024, 512, 0, stream>>>(offs, cursor, btot, 410, NCNT);
  fill_sh<<<2048, 256, 0, stream>>>(R, cursor, csr);

  float* out = (float*)d_out;
  const float* bA = (const float*)d_in[19];
  const float* bF = (const float*)d_in[21];
  const float* bI = (const float*)d_in[23];
  const float* bP = (const float*)d_in[25];

  if (useBF) {
    fused_all<<<NB_TOTAL, 256, 0, stream>>>(xbA, xbF, xbI, xbP, wt,
                                            offs, cnt, csr,
                                            bA, bF, bI, bP, out);
  } else {
    fb_gemm<<<NBA, 256, 0, stream>>>(
        x_author, x_inst, x_paper, nullptr,
        wt + 0 * 16384, wt + 5 * 16384, wt + 7 * 16384, nullptr,
        3, B_ITA, B_PTA, 0, offs, cnt, csr, bA, out, N_AUTHOR);
    fb_gemm<<<NBF, 256, 0, stream>>>(
        x_fos, x_paper, nullptr, nullptr,
        wt + 1 * 16384, wt + 9 * 16384, nullptr, nullptr,
        2, B_TOPIC, 0, 0, offs, cnt, csr, bF, out + (size_t)100000 * 128, N_FOS);
    fb_gemm<<<NBI, 256, 0, stream>>>(
        x_inst, x_author, nullptr, nullptr,
        wt + 2 * 16384, wt + 4 * 16384, nullptr, nullptr,
        2, B_AFF, 0, 0, offs, cnt, csr, bI, out + (size_t)130000 * 128, N_INST);
    fb_gemm<<<NBP, 256, 0, stream>>>(
        x_paper, x_author, x_paper, x_fos,
        wt + 3 * 16384, wt + 6 * 16384, wt + 8 * 16384, wt + 10 * 16384,
        4, B_WRITES, B_CITES, B_FTP, offs, cnt, csr, bP,
        out + (size_t)138000 * 128, N_PAPER);
  }
}

// Round 15
// 817.875 us; speedup vs baseline: 1.3609x; 1.0092x over previous
//
#include <hip/hip_runtime.h>

#define N_AUTHOR 100000
#define N_FOS    30000
#define N_INST   8000
#define N_PAPER  200000
#define NCNT     838000
#define ETOT     3300000
#define NSHARD   (NCNT / 8)

#define NBA 1563
#define NBF 469
#define NBI 125
#define NBP 3125
#define NB_TOTAL (NBP + NBA + NBF + NBI)

#define B_AFF    0
#define B_ITA    8000
#define B_WRITES 108000
#define B_PTA    308000
#define B_CITES  408000
#define B_TOPIC  608000
#define B_FTP    638000

typedef __attribute__((ext_vector_type(8))) short short8v;
typedef __attribute__((ext_vector_type(4))) float float4v;
typedef unsigned short us;

__device__ __forceinline__ us f2bf(float f) {
  unsigned u = __float_as_uint(f);
  u = u + 0x7fffu + ((u >> 16) & 1u);
  return (us)(u >> 16);
}
#define BF2F(s) __uint_as_float(((unsigned)(us)(s)) << 16)

__device__ __forceinline__ void acc8(float4v& x, float4v& y, short8v h) {
  x[0] += BF2F(h[0]); x[1] += BF2F(h[1]); x[2] += BF2F(h[2]); x[3] += BF2F(h[3]);
  y[0] += BF2F(h[4]); y[1] += BF2F(h[5]); y[2] += BF2F(h[6]); y[3] += BF2F(h[7]);
}

__device__ __forceinline__ short8v pack8(float4v a, float4v b) {
  short8v h;
  h[0] = (short)f2bf(a[0]); h[1] = (short)f2bf(a[1]);
  h[2] = (short)f2bf(a[2]); h[3] = (short)f2bf(a[3]);
  h[4] = (short)f2bf(b[0]); h[5] = (short)f2bf(b[1]);
  h[6] = (short)f2bf(b[2]); h[7] = (short)f2bf(b[3]);
  return h;
}

// ---------------- workspace layout (bytes) ----------------
#define O_CNT    0
#define O_OFFS   3352000
#define O_CURSOR 6704000
#define O_BTOT   10056000
#define O_CSR    10060096
#define O_WT     23260096
#define XB_AUTHOR 23620544
#define XB_FOS    49220544
#define XB_INST   56900544
#define XB_PAPER  58948544
#define WS_NEED_BF 110148544ULL

struct RelTab { const int* src; const int* dst; int E; int base; };
struct Rels { RelTab r[7]; };
struct WPtrs { const float* w[11]; };
struct XCvt { const float* x; us* xb; int n8; };

// prep: W transpose+bf16, x fp32->bf16, PLUS XCD-sharded edge counting.
__global__ __launch_bounds__(256, 8) void prep(WPtrs P, us* __restrict__ wt,
                     int* __restrict__ cnt,
                     XCvt x0, XCvt x1, XCvt x2, XCvt x3,
                     Rels R, int doX) {
  int gsz = gridDim.x * blockDim.x;
  int gtid = blockIdx.x * blockDim.x + threadIdx.x;
  for (int i = gtid; i < 11 * 16384; i += gsz) {
    int mat = i >> 14, rem = i & 16383;
    int k = rem >> 7, n = rem & 127;
    wt[mat * 16384 + n * 128 + k] = f2bf(P.w[mat][rem]);
  }
  if (doX) {
    XCvt xc[4] = {x0, x1, x2, x3};
    #pragma unroll
    for (int a = 0; a < 4; ++a) {
      const float* xp = xc[a].x;
      short8v* xbp = (short8v*)xc[a].xb;
      int n8 = xc[a].n8;
      for (int i = gtid; i < n8; i += gsz) {
        float4v v0 = *(const float4v*)(xp + (size_t)i * 8);
        float4v v1 = *(const float4v*)(xp + (size_t)i * 8 + 4);
        xbp[i] = pack8(v0, v1);
      }
    }
  }
  const int cls = blockIdx.x & 7;
  const int lo = cls * NSHARD;
  const int hi = lo + NSHARD;
  const int sgsz = (gridDim.x >> 3) * 256;
  const int sgtid = (blockIdx.x >> 3) * 256 + threadIdx.x;
  #pragma unroll
  for (int rr = 0; rr < 7; ++rr) {
    const int* __restrict__ dst = R.r[rr].dst;
    const int E = R.r[rr].E, base = R.r[rr].base;
    for (int e = sgtid; e < E; e += sgsz) {
      int gd = base + dst[e];
      if (gd >= lo && gd < hi) atomicAdd(&cnt[gd], 1);
    }
  }
}

__global__ void scan1(const int* __restrict__ cnt, int* __restrict__ offs,
                      int* __restrict__ btot, int n) {
  __shared__ int sh[256];
  int tid = threadIdx.x;
  int base = blockIdx.x * 2048 + tid * 8;
  int v[8]; int s = 0;
  #pragma unroll
  for (int i = 0; i < 8; ++i) { v[i] = (base + i < n) ? cnt[base + i] : 0; s += v[i]; }
  sh[tid] = s; __syncthreads();
  for (int off = 1; off < 256; off <<= 1) {
    int t = (tid >= off) ? sh[tid - off] : 0;
    __syncthreads();
    sh[tid] += t;
    __syncthreads();
  }
  int excl = sh[tid] - s;
  if (tid == 255) btot[blockIdx.x] = sh[255];
  int run = excl;
  #pragma unroll
  for (int i = 0; i < 8; ++i) { if (base + i < n) offs[base + i] = run; run += v[i]; }
}

__global__ void scan23(int* __restrict__ offs, int* __restrict__ cursor,
                       const int* __restrict__ btot, int nb, int n) {
  __shared__ int sh[512];
  int tid = threadIdx.x;
  int v = (tid < nb) ? btot[tid] : 0;
  sh[tid] = v; __syncthreads();
  for (int off = 1; off < 512; off <<= 1) {
    int t = (tid >= off) ? sh[tid - off] : 0;
    __syncthreads();
    sh[tid] += t;
    __syncthreads();
  }
  int excl = sh[tid] - v;
  __syncthreads();
  sh[tid] = excl;
  __syncthreads();
  int gsz = gridDim.x * 512;
  for (int idx = blockIdx.x * 512 + tid; idx < n; idx += gsz) {
    int val = offs[idx] + sh[idx >> 11];
    offs[idx] = val;
    cursor[idx] = val;
  }
}

__global__ __launch_bounds__(256, 8) void fill_sh(Rels R, int* __restrict__ cursor,
                                                  int* __restrict__ csr) {
  const int cls = blockIdx.x & 7;
  const int lo = cls * NSHARD;
  const int hi = lo + NSHARD;
  const int gsz = (gridDim.x >> 3) * 256;
  const int gtid = (blockIdx.x >> 3) * 256 + threadIdx.x;
  #pragma unroll
  for (int rr = 0; rr < 7; ++rr) {
    const int* __restrict__ src = R.r[rr].src;
    const int* __restrict__ dst = R.r[rr].dst;
    const int E = R.r[rr].E, base = R.r[rr].base;
    for (int e = gtid; e < E; e += gsz) {
      int gd = base + dst[e];
      if (gd >= lo && gd < hi) {
        int p = atomicAdd(&cursor[gd], 1);
        csr[p] = src[e];
      }
    }
  }
}

// -------- fused gather-GEMM body: 2-edge batching + idx prefetch + hoist ----
template <int NSRC>
__device__ __forceinline__ void fused_body(
    const us* __restrict__ x0, const us* __restrict__ x1,
    const us* __restrict__ x2, const us* __restrict__ x3,
    const us* __restrict__ w0, const us* __restrict__ w1,
    const us* __restrict__ w2, const us* __restrict__ w3,
    int b1, int b2, int b3,
    const int* __restrict__ offs, const int* __restrict__ cnt,
    const int* __restrict__ csr,
    const float* __restrict__ bias, float* __restrict__ out, int n, int rb0) {
  const int lane = threadIdx.x & 63;
  const int wv = threadIdx.x >> 6;
  const int rb = rb0 + wv * 16;
  int ar = rb + (lane & 15); if (ar >= n) ar = n - 1;
  const int cw = (lane >> 4) * 8;

  const us* xs[4] = {x0, x1, x2, x3};
  const us* wsp[4] = {w0, w1, w2, w3};
  const int bases[4] = {0, b1, b2, b3};

  // hoist CSR metadata loads for all relation blocks (independent, overlap)
  int stA[4], dgA[4];
  #pragma unroll
  for (int kb = 1; kb < NSRC; ++kb) {
    int gd = bases[kb] + ar;
    stA[kb] = offs[gd];
    dgA[kb] = cnt[gd];
  }

  float4v acc[8];
  #pragma unroll
  for (int i = 0; i < 8; ++i) acc[i] = (float4v)0.0f;

  #pragma unroll
  for (int kb = 0; kb < NSRC; ++kb) {
    short8v af[4];
    if (kb == 0) {
      const us* rp = xs[0] + (size_t)ar * 128 + cw;
      #pragma unroll
      for (int ks = 0; ks < 4; ++ks)
        af[ks] = *(const short8v*)(rp + ks * 32);
    } else {
      const int st = stA[kb], deg = dgA[kb];
      const us* xb = xs[kb];
      float4v a0[4], a1[4];
      #pragma unroll
      for (int ks = 0; ks < 4; ++ks) { a0[ks] = (float4v)0.f; a1[ks] = (float4v)0.f; }
      int j = 0;
      int s0 = 0, s1 = 0;
      if (deg >= 2) { s0 = csr[st]; s1 = csr[st + 1]; }
      for (; j + 2 <= deg; j += 2) {
        const us* p0 = xb + (size_t)s0 * 128 + cw;
        const us* p1 = xb + (size_t)s1 * 128 + cw;
        // prefetch next batch's indices; hides under the row-load wait
        if (j + 4 <= deg) { s0 = csr[st + j + 2]; s1 = csr[st + j + 3]; }
        #pragma unroll
        for (int ks = 0; ks < 4; ++ks) {
          short8v h0 = *(const short8v*)(p0 + ks * 32);
          short8v h1 = *(const short8v*)(p1 + ks * 32);
          acc8(a0[ks], a1[ks], h0);
          acc8(a0[ks], a1[ks], h1);
        }
      }
      if (j < deg) {
        int sl = csr[st + j];
        const us* p0 = xb + (size_t)sl * 128 + cw;
        #pragma unroll
        for (int ks = 0; ks < 4; ++ks) {
          short8v h0 = *(const short8v*)(p0 + ks * 32);
          acc8(a0[ks], a1[ks], h0);
        }
      }
      float sc = 1.0f / (float)((deg > 0) ? deg : 1);
      #pragma unroll
      for (int ks = 0; ks < 4; ++ks)
        af[ks] = pack8(a0[ks] * sc, a1[ks] * sc);
    }
    const us* wb = wsp[kb] + (size_t)(lane & 15) * 128 + cw;
    #pragma unroll
    for (int ct = 0; ct < 8; ++ct) {
      short8v bfr[4];
      #pragma unroll
      for (int ks = 0; ks < 4; ++ks)
        bfr[ks] = *(const short8v*)(wb + ct * 2048 + ks * 32);
      #pragma unroll
      for (int ks = 0; ks < 4; ++ks)
        acc[ct] = __builtin_amdgcn_mfma_f32_16x16x32_bf16(af[ks], bfr[ks], acc[ct], 0, 0, 0);
    }
  }
  #pragma unroll
  for (int ct = 0; ct < 8; ++ct) {
    #pragma unroll
    for (int i = 0; i < 4; ++i) {
      int g = rb + (lane >> 4) * 4 + i;
      if (g < n) {
        int col = ct * 16 + (lane & 15);
        out[(size_t)g * 128 + col] = acc[ct][i] + bias[col];
      }
    }
  }
}

__global__ __launch_bounds__(256, 6) void fused_all(
    const us* __restrict__ xbA, const us* __restrict__ xbF,
    const us* __restrict__ xbI, const us* __restrict__ xbP,
    const us* __restrict__ wt,
    const int* __restrict__ offs, const int* __restrict__ cnt,
    const int* __restrict__ csr,
    const float* __restrict__ bA, const float* __restrict__ bF,
    const float* __restrict__ bI, const float* __restrict__ bP,
    float* __restrict__ out) {
  const int bid = blockIdx.x;
  if (bid < NBP) {
    fused_body<4>(xbP, xbA, xbP, xbF,
                  wt + 3 * 16384, wt + 6 * 16384, wt + 8 * 16384, wt + 10 * 16384,
                  B_WRITES, B_CITES, B_FTP, offs, cnt, csr,
                  bP, out + (size_t)138000 * 128, N_PAPER, bid * 64);
  } else if (bid < NBP + NBA) {
    fused_body<3>(xbA, xbI, xbP, nullptr,
                  wt + 0 * 16384, wt + 5 * 16384, wt + 7 * 16384, nullptr,
                  B_ITA, B_PTA, 0, offs, cnt, csr,
                  bA, out, N_AUTHOR, (bid - NBP) * 64);
  } else if (bid < NBP + NBA + NBF) {
    fused_body<2>(xbF, xbP, nullptr, nullptr,
                  wt + 1 * 16384, wt + 9 * 16384, nullptr, nullptr,
                  B_TOPIC, 0, 0, offs, cnt, csr,
                  bF, out + (size_t)100000 * 128, N_FOS, (bid - NBP - NBA) * 64);
  } else {
    fused_body<2>(xbI, xbA, nullptr, nullptr,
                  wt + 2 * 16384, wt + 4 * 16384, nullptr, nullptr,
                  B_AFF, 0, 0, offs, cnt, csr,
                  bI, out + (size_t)130000 * 128, N_INST, (bid - NBP - NBA - NBF) * 64);
  }
}

// ---------------- fp32 fallback (small ws) ----------------------------------
typedef float4v f4;
__global__ __launch_bounds__(256, 4) void fb_gemm(
    const float* __restrict__ x0, const float* __restrict__ x1,
    const float* __restrict__ x2, const float* __restrict__ x3,
    const us* __restrict__ w0, const us* __restrict__ w1,
    const us* __restrict__ w2, const us* __restrict__ w3,
    int nsrc, int b1, int b2, int b3,
    const int* __restrict__ offs, const int* __restrict__ cnt,
    const int* __restrict__ csr,
    const float* __restrict__ bias, float* __restrict__ out, int n) {
  const int lane = threadIdx.x & 63;
  const int wv = threadIdx.x >> 6;
  const int rb = blockIdx.x * 64 + wv * 16;
  int ar = rb + (lane & 15); if (ar >= n) ar = n - 1;
  const int cw = (lane >> 4) * 8;
  const float* xs[4] = {x0, x1, x2, x3};
  const us* wsp[4] = {w0, w1, w2, w3};
  const int bases[4] = {0, b1, b2, b3};
  float4v acc[8];
  #pragma unroll
  for (int i = 0; i < 8; ++i) acc[i] = (float4v)0.0f;
  for (int kb = 0; kb < nsrc; ++kb) {
    short8v af[4];
    const float* xb = xs[kb];
    if (kb == 0) {
      const float* rp = xb + (size_t)ar * 128 + cw;
      #pragma unroll
      for (int ks = 0; ks < 4; ++ks) {
        f4 u = *(const f4*)(rp + ks * 32);
        f4 v = *(const f4*)(rp + ks * 32 + 4);
        af[ks] = pack8(u, v);
      }
    } else {
      int gd = bases[kb] + ar;
      int st = offs[gd];
      int deg = cnt[gd];
      f4 a0[4], a1[4];
      #pragma unroll
      for (int ks = 0; ks < 4; ++ks) { a0[ks] = (f4)0.f; a1[ks] = (f4)0.f; }
      for (int j = 0; j < deg; ++j) {
        int s0 = csr[st + j];
        const float* p0 = xb + (size_t)s0 * 128 + cw;
        #pragma unroll
        for (int ks = 0; ks < 4; ++ks) {
          a0[ks] += *(const f4*)(p0 + ks * 32);
          a1[ks] += *(const f4*)(p0 + ks * 32 + 4);
        }
      }
      float sc = 1.0f / (float)((deg > 0) ? deg : 1);
      #pragma unroll
      for (int ks = 0; ks < 4; ++ks)
        af[ks] = pack8(a0[ks] * sc, a1[ks] * sc);
    }
    const us* wb = wsp[kb] + (size_t)(lane & 15) * 128 + cw;
    #pragma unroll
    for (int ct = 0; ct < 8; ++ct) {
      short8v bfr[4];
      #pragma unroll
      for (int ks = 0; ks < 4; ++ks)
        bfr[ks] = *(const short8v*)(wb + ct * 2048 + ks * 32);
      #pragma unroll
      for (int ks = 0; ks < 4; ++ks)
        acc[ct] = __builtin_amdgcn_mfma_f32_16x16x32_bf16(af[ks], bfr[ks], acc[ct], 0, 0, 0);
    }
  }
  #pragma unroll
  for (int ct = 0; ct < 8; ++ct) {
    #pragma unroll
    for (int i = 0; i < 4; ++i) {
      int g = rb + (lane >> 4) * 4 + i;
      if (g < n) {
        int col = ct * 16 + (lane & 15);
        out[(size_t)g * 128 + col] = acc[ct][i] + bias[col];
      }
    }
  }
}

extern "C" void kernel_launch(void* const* d_in, const int* in_sizes, int n_in,
                              void* d_out, int out_size, void* d_ws, size_t ws_size,
                              hipStream_t stream) {
  const float* x_author = (const float*)d_in[0];
  const float* x_fos    = (const float*)d_in[1];
  const float* x_inst   = (const float*)d_in[2];
  const float* x_paper  = (const float*)d_in[3];

  Rels R;
  const int E[7]  = {150000, 150000, 500000, 500000, 1000000, 500000, 500000};
  const int ND[7] = {N_INST, N_AUTHOR, N_PAPER, N_AUTHOR, N_PAPER, N_FOS, N_PAPER};
  int base = 0;
  for (int r = 0; r < 7; ++r) {
    R.r[r].src = (const int*)d_in[4 + 2 * r];
    R.r[r].dst = (const int*)d_in[5 + 2 * r];
    R.r[r].E = E[r];
    R.r[r].base = base;
    base += ND[r];
  }

  char* ws = (char*)d_ws;
  int* cnt    = (int*)(ws + O_CNT);
  int* offs   = (int*)(ws + O_OFFS);
  int* cursor = (int*)(ws + O_CURSOR);
  int* btot   = (int*)(ws + O_BTOT);
  int* csr    = (int*)(ws + O_CSR);
  us* wt  = (us*)(ws + O_WT);
  us* xbA = (us*)(ws + XB_AUTHOR);
  us* xbF = (us*)(ws + XB_FOS);
  us* xbI = (us*)(ws + XB_INST);
  us* xbP = (us*)(ws + XB_PAPER);

  const int useBF = (ws_size >= WS_NEED_BF) ? 1 : 0;

  WPtrs WP;
  WP.w[0] = (const float*)d_in[18];
  WP.w[1] = (const float*)d_in[20];
  WP.w[2] = (const float*)d_in[22];
  WP.w[3] = (const float*)d_in[24];
  for (int r = 0; r < 7; ++r) WP.w[4 + r] = (const float*)d_in[26 + r];

  XCvt xcA = {x_author, xbA, N_AUTHOR * 16};
  XCvt xcF = {x_fos,    xbF, N_FOS * 16};
  XCvt xcI = {x_inst,   xbI, N_INST * 16};
  XCvt xcP = {x_paper,  xbP, N_PAPER * 16};

  hipMemsetAsync(cnt, 0, (size_t)NCNT * 4, stream);
  prep<<<2048, 256, 0, stream>>>(WP, wt, cnt, xcA, xcF, xcI, xcP, R, useBF);
  scan1<<<410, 256, 0, stream>>>(cnt, offs, btot, NCNT);
  scan23<<<1024, 512, 0, stream>>>(offs, cursor, btot, 410, NCNT);
  fill_sh<<<2048, 256, 0, stream>>>(R, cursor, csr);

  float* out = (float*)d_out;
  const float* bA = (const float*)d_in[19];
  const float* bF = (const float*)d_in[21];
  const float* bI = (const float*)d_in[23];
  const float* bP = (const float*)d_in[25];

  if (useBF) {
    fused_all<<<NB_TOTAL, 256, 0, stream>>>(xbA, xbF, xbI, xbP, wt,
                                            offs, cnt, csr,
                                            bA, bF, bI, bP, out);
  } else {
    fb_gemm<<<NBA, 256, 0, stream>>>(
        x_author, x_inst, x_paper, nullptr,
        wt + 0 * 16384, wt + 5 * 16384, wt + 7 * 16384, nullptr,
        3, B_ITA, B_PTA, 0, offs, cnt, csr, bA, out, N_AUTHOR);
    fb_gemm<<<NBF, 256, 0, stream>>>(
        x_fos, x_paper, nullptr, nullptr,
        wt + 1 * 16384, wt + 9 * 16384, nullptr, nullptr,
        2, B_TOPIC, 0, 0, offs, cnt, csr, bF, out + (size_t)100000 * 128, N_FOS);
    fb_gemm<<<NBI, 256, 0, stream>>>(
        x_inst, x_author, nullptr, nullptr,
        wt + 2 * 16384, wt + 4 * 16384, nullptr, nullptr,
        2, B_AFF, 0, 0, offs, cnt, csr, bI, out + (size_t)130000 * 128, N_INST);
    fb_gemm<<<NBP, 256, 0, stream>>>(
        x_paper, x_author, x_paper, x_fos,
        wt + 3 * 16384, wt + 6 * 16384, wt + 8 * 16384, wt + 10 * 16384,
        4, B_WRITES, B_CITES, B_FTP, offs, cnt, csr, bP,
        out + (size_t)138000 * 128, N_PAPER);
  }
}